// Round 1
// baseline (1379.097 us; speedup 1.0000x reference)
//
#include <hip/hip_runtime.h>
#include <cstdint>

// ---------------------------------------------------------------------------
// Mamba block: xz=x@W_in^T -> split(xp,z) -> causal depthwise conv4+silu ->
// dbc=xc@W_x^T -> split(dt,B,C) -> delta=softplus(dt@W_dt^T+b_dt) ->
// diagonal SSM scan -> y=(sum_s h*C + xc*D)*silu(z) -> out=y@W_out^T
// Shapes: B=2,L=1024 (M=2048), D_MODEL=2048, D_INNER=4096, D_STATE=16,
// DT_RANK=128, D_CONV=4.
// ---------------------------------------------------------------------------

typedef __bf16 bf16x8 __attribute__((ext_vector_type(8)));
typedef float f32x4 __attribute__((ext_vector_type(4)));

__device__ __forceinline__ unsigned short f2bf(float f) {
  uint32_t u = __float_as_uint(f);
  u += 0x7FFFu + ((u >> 16) & 1u);   // round-to-nearest-even
  return (unsigned short)(u >> 16);
}

__device__ __forceinline__ float silu_f(float v) {
  return v / (1.f + __expf(-v));
}

// ---------------- cast kernels ----------------
__global__ void cast_f32_to_bf16(const float* __restrict__ src,
                                 unsigned short* __restrict__ dst, int n4) {
  int i = blockIdx.x * 256 + threadIdx.x;
  if (i >= n4) return;
  float4 v = reinterpret_cast<const float4*>(src)[i];
  ushort4 o;
  o.x = f2bf(v.x); o.y = f2bf(v.y); o.z = f2bf(v.z); o.w = f2bf(v.w);
  reinterpret_cast<ushort4*>(dst)[i] = o;
}

// W_x is [160][4096]; pad to [256][4096] with zero rows so GEMM2 needs no guards.
__global__ void cast_wx_pad(const float* __restrict__ Wx,
                            unsigned short* __restrict__ dst) {
  int i = blockIdx.x * 256 + threadIdx.x;   // over 256*4096
  int r = i >> 12;
  float v = (r < 160) ? Wx[(size_t)r * 4096 + (i & 4095)] : 0.f;
  dst[i] = f2bf(v);
}

// dt = dbc[:, 0:128] -> bf16 [2048][128]
__global__ void cast_dt(const float* __restrict__ dbc,
                        unsigned short* __restrict__ dst) {
  int i = blockIdx.x * 256 + threadIdx.x;   // over 2048*128
  int m = i >> 7, r = i & 127;
  dst[i] = f2bf(dbc[(size_t)m * 256 + r]);
}

// ---------------- bf16 MFMA GEMM: C[M][N] = A[M][K] * B[N][K]^T ----------------
// m97-style: 128x128 tile, BK=32, 256 threads (4 waves 2x2, each 64x64),
// global_load_lds width-16 staging, 16x16x32 bf16 MFMA, fp32 accum.
#define BM 128
#define BN 128
#define BKK 32

__device__ __forceinline__ void stage_tile(const unsigned short* __restrict__ G,
                                           int ldK, int g0, int k0,
                                           unsigned short* lds, int wave, int lane) {
#pragma unroll
  for (int c = 0; c < 2; ++c) {
    // LDS dest is wave-uniform base + lane*16 (HW-defined): byte off =
    // c*4096 + wave*1024 + lane*16  ->  row = c*64 + wave*16 + lane/4, col8 = lane%4
    int row = c * 64 + wave * 16 + (lane >> 2);
    int col = (lane & 3) * 8;
    const unsigned short* src = G + (size_t)(g0 + row) * ldK + (k0 + col);
    unsigned short* dst = lds + c * 2048 + wave * 512;  // ushort units
    __builtin_amdgcn_global_load_lds((__attribute__((address_space(1))) void*)(src),
                                     (__attribute__((address_space(3))) void*)(dst),
                                     16, 0, 0);
  }
}

__global__ __launch_bounds__(256)
void gemm_bt(const unsigned short* __restrict__ A, const unsigned short* __restrict__ B,
             float* __restrict__ C, int M, int N, int K) {
  __shared__ unsigned short As[BM * BKK];
  __shared__ unsigned short Bs[BN * BKK];
  const int tid = threadIdx.x;
  const int wave = tid >> 6, lane = tid & 63;
  const int wr = wave >> 1, wc = wave & 1;   // 2x2 waves, each owns 64x64 output
  const int m0 = blockIdx.y * BM, n0 = blockIdx.x * BN;
  const int lr = lane & 15, lg = lane >> 4;

  f32x4 zero = {0.f, 0.f, 0.f, 0.f};
  f32x4 acc[4][4];
#pragma unroll
  for (int i = 0; i < 4; ++i)
#pragma unroll
    for (int j = 0; j < 4; ++j) acc[i][j] = zero;

  for (int k0 = 0; k0 < K; k0 += BKK) {
    stage_tile(A, K, m0, k0, As, wave, lane);
    stage_tile(B, K, n0, k0, Bs, wave, lane);
    __syncthreads();   // drains vmcnt (global_load_lds) + lgkm
    bf16x8 af[4], bfr[4];
#pragma unroll
    for (int i = 0; i < 4; ++i)
      af[i] = *reinterpret_cast<const bf16x8*>(&As[(wr * 64 + i * 16 + lr) * BKK + lg * 8]);
#pragma unroll
    for (int j = 0; j < 4; ++j)
      bfr[j] = *reinterpret_cast<const bf16x8*>(&Bs[(wc * 64 + j * 16 + lr) * BKK + lg * 8]);
#pragma unroll
    for (int i = 0; i < 4; ++i)
#pragma unroll
      for (int j = 0; j < 4; ++j)
        acc[i][j] = __builtin_amdgcn_mfma_f32_16x16x32_bf16(af[i], bfr[j], acc[i][j], 0, 0, 0);
    __syncthreads();
  }

  // C/D layout (m89-verified): col = lane&15, row = (lane>>4)*4 + reg
#pragma unroll
  for (int i = 0; i < 4; ++i) {
#pragma unroll
    for (int j = 0; j < 4; ++j) {
      int mrow = m0 + wr * 64 + i * 16 + lg * 4;
      int ncol = n0 + wc * 64 + j * 16 + lr;
#pragma unroll
      for (int r = 0; r < 4; ++r)
        C[(size_t)(mrow + r) * N + ncol] = acc[i][j][r];
    }
  }
}

// ---------------- conv(4, causal, depthwise) + silu ----------------
// xz: [2048][8192] fp32, xp = cols [0,4096). Writes xc fp32 + xc bf16.
__global__ void conv_silu_kernel(const float* __restrict__ xz,
                                 const float* __restrict__ conv_w,
                                 const float* __restrict__ conv_b,
                                 float* __restrict__ xc,
                                 unsigned short* __restrict__ xc_bf) {
  int idx = blockIdx.x * 256 + threadIdx.x;  // over 2048*4096
  int e = idx & 4095;
  int m = idx >> 12;
  int l = m & 1023;                          // within-batch position
  float acc = conv_b[e];
#pragma unroll
  for (int k = 0; k < 4; ++k) {
    int ls = l - 3 + k;
    if (ls >= 0) acc = fmaf(xz[(size_t)(m - 3 + k) * 8192 + e], conv_w[e * 4 + k], acc);
  }
  float s = silu_f(acc);
  xc[idx] = s;
  xc_bf[idx] = f2bf(s);
}

// ---------------- SSM scan ----------------
// block = 256 threads = 16 channels x 16 states. grid = B * (4096/16) = 512.
// Per l: delta=softplus(delta_pre+b_dt); h[s]=exp(delta*A[s])*h[s]+delta*B[s]*xc;
// y = (sum_s h[s]*C[s] + xc*D) * silu(z). Writes y as bf16 (GEMM4 A operand).
__global__ __launch_bounds__(256)
void scan_kernel(const float* __restrict__ delta_pre, const float* __restrict__ b_dt,
                 const float* __restrict__ dbc, const float* __restrict__ xc,
                 const float* __restrict__ xz, const float* __restrict__ A_log,
                 const float* __restrict__ Dp, unsigned short* __restrict__ y_bf) {
  int t = threadIdx.x;
  int s = t & 15, eo = t >> 4;
  int b = blockIdx.x >> 8;
  int e = (blockIdx.x & 255) * 16 + eo;
  float A = -__expf(A_log[e * 16 + s]);
  float bdt = b_dt[e];
  float Dv = Dp[e];
  float h = 0.f;
  size_t m = (size_t)b * 1024;
  for (int l = 0; l < 1024; ++l, ++m) {
    float dp  = delta_pre[m * 4096 + e];   // same addr across the 16-lane group
    float xcv = xc[m * 4096 + e];
    float Bv  = dbc[m * 256 + 128 + s];
    float Cv  = dbc[m * 256 + 144 + s];
    float x1 = dp + bdt;
    float delta = (x1 > 20.f) ? x1 : log1pf(__expf(x1));
    float dA = __expf(delta * A);
    h = fmaf(dA, h, delta * Bv * xcv);
    float part = h * Cv;
    part += __shfl_xor(part, 1);
    part += __shfl_xor(part, 2);
    part += __shfl_xor(part, 4);
    part += __shfl_xor(part, 8);
    if (s == 0) {
      float z = xz[m * 8192 + 4096 + e];
      float y = (part + xcv * Dv) * silu_f(z);
      y_bf[m * 4096 + e] = f2bf(y);
    }
  }
}

// ---------------------------------------------------------------------------
extern "C" void kernel_launch(void* const* d_in, const int* in_sizes, int n_in,
                              void* d_out, int out_size, void* d_ws, size_t ws_size,
                              hipStream_t stream) {
  const float* x      = (const float*)d_in[0];
  const float* W_in   = (const float*)d_in[1];
  const float* conv_w = (const float*)d_in[2];
  const float* conv_b = (const float*)d_in[3];
  const float* W_x    = (const float*)d_in[4];
  const float* W_dt   = (const float*)d_in[5];
  const float* b_dt   = (const float*)d_in[6];
  const float* A_log  = (const float*)d_in[7];
  const float* Dp     = (const float*)d_in[8];
  const float* W_out  = (const float*)d_in[9];
  float* out = (float*)d_out;
  char* ws = (char*)d_ws;

  // workspace layout (190,316,544 bytes total; two time-disjoint aliases)
  unsigned short* Win_bf    = (unsigned short*)(ws + 0);          // 33.55 MB
  float*          delta_pre = (float*)(ws + 0);                   // alias (after GEMM1)
  unsigned short* x_bf      = (unsigned short*)(ws + 33554432);   // 8.39 MB used
  unsigned short* y_bf      = (unsigned short*)(ws + 33554432);   // alias (after GEMM1)
  unsigned short* Wout_bf   = (unsigned short*)(ws + 50331648);   // 16.78 MB
  unsigned short* Wx_bf     = (unsigned short*)(ws + 67108864);   // 2.10 MB (padded 256 rows)
  unsigned short* Wdt_bf    = (unsigned short*)(ws + 69206016);   // 1.05 MB
  float*          xz        = (float*)(ws + 70254592);            // 67.11 MB
  float*          xc        = (float*)(ws + 137363456);           // 33.55 MB
  unsigned short* xc_bf     = (unsigned short*)(ws + 170917888);  // 16.78 MB
  float*          dbc       = (float*)(ws + 187695104);           // 2.10 MB ([2048][256], cols 160+ are 0)
  unsigned short* dt_bf     = (unsigned short*)(ws + 189792256);  // 0.52 MB

  // casts (bf16 operands for MFMA GEMMs)
  cast_f32_to_bf16<<<4096, 256, 0, stream>>>(x, x_bf, 1048576);
  cast_f32_to_bf16<<<16384, 256, 0, stream>>>(W_in, Win_bf, 4194304);
  cast_f32_to_bf16<<<8192, 256, 0, stream>>>(W_out, Wout_bf, 2097152);
  cast_wx_pad<<<4096, 256, 0, stream>>>(W_x, Wx_bf);
  cast_f32_to_bf16<<<512, 256, 0, stream>>>(W_dt, Wdt_bf, 131072);

  // GEMM1: xz[2048][8192] = x[2048][2048] @ W_in[8192][2048]^T
  gemm_bt<<<dim3(64, 16), 256, 0, stream>>>(x_bf, Win_bf, xz, 2048, 8192, 2048);

  // conv + silu -> xc (fp32 + bf16)
  conv_silu_kernel<<<32768, 256, 0, stream>>>(xz, conv_w, conv_b, xc, xc_bf);

  // GEMM2: dbc[2048][256] = xc[2048][4096] @ Wx_pad[256][4096]^T
  gemm_bt<<<dim3(2, 16), 256, 0, stream>>>(xc_bf, Wx_bf, dbc, 2048, 256, 4096);

  // dt -> bf16
  cast_dt<<<1024, 256, 0, stream>>>(dbc, dt_bf);

  // GEMM3: delta_pre[2048][4096] = dt[2048][128] @ W_dt[4096][128]^T
  gemm_bt<<<dim3(32, 16), 256, 0, stream>>>(dt_bf, Wdt_bf, delta_pre, 2048, 4096, 128);

  // SSM scan -> y_bf
  scan_kernel<<<512, 256, 0, stream>>>(delta_pre, b_dt, dbc, xc, xz, A_log, Dp, y_bf);

  // GEMM4: out[2048][2048] = y[2048][4096] @ W_out[2048][4096]^T
  gemm_bt<<<dim3(16, 16), 256, 0, stream>>>(y_bf, Wout_bf, out, 2048, 2048, 4096);
}

// Round 3
// 496.437 us; speedup vs baseline: 2.7780x; 2.7780x over previous
//
#include <hip/hip_runtime.h>
#include <cstdint>

// ---------------------------------------------------------------------------
// Mamba block: xz=x@W_in^T -> split(xp,z) -> causal depthwise conv4+silu ->
// dbc=xc@W_x^T -> split(dt,B,C) -> delta=softplus(dt@W_dt^T+b_dt) ->
// diagonal SSM scan (chunked, 2-pass) -> y=(sum_s h*C + xc*D)*silu(z) ->
// out=y@W_out^T
// Shapes: B=2,L=1024 (M=2048), D_MODEL=2048, D_INNER=4096, D_STATE=16,
// DT_RANK=128, D_CONV=4. Chunks: 16 per batch, 64 steps each.
// ---------------------------------------------------------------------------

typedef __bf16 bf16x8 __attribute__((ext_vector_type(8)));
typedef float f32x4 __attribute__((ext_vector_type(4)));

__device__ __forceinline__ unsigned short f2bf(float f) {
  uint32_t u = __float_as_uint(f);
  u += 0x7FFFu + ((u >> 16) & 1u);   // round-to-nearest-even
  return (unsigned short)(u >> 16);
}

__device__ __forceinline__ float silu_f(float v) {
  return v / (1.f + __expf(-v));
}

__device__ __forceinline__ float softplus_f(float v) {
  return (v > 20.f) ? v : log1pf(__expf(v));
}

// ---------------- cast kernels ----------------
__global__ void cast_f32_to_bf16(const float* __restrict__ src,
                                 unsigned short* __restrict__ dst, int n4) {
  int i = blockIdx.x * 256 + threadIdx.x;
  if (i >= n4) return;
  float4 v = reinterpret_cast<const float4*>(src)[i];
  ushort4 o;
  o.x = f2bf(v.x); o.y = f2bf(v.y); o.z = f2bf(v.z); o.w = f2bf(v.w);
  reinterpret_cast<ushort4*>(dst)[i] = o;
}

// W_x is [160][4096]; pad to [256][4096] with zero rows so GEMM2 needs no guards.
__global__ void cast_wx_pad(const float* __restrict__ Wx,
                            unsigned short* __restrict__ dst) {
  int i = blockIdx.x * 256 + threadIdx.x;   // over 256*4096
  int r = i >> 12;
  float v = (r < 160) ? Wx[(size_t)r * 4096 + (i & 4095)] : 0.f;
  dst[i] = f2bf(v);
}

// dt = dbc[:, 0:128] -> bf16 [2048][128]
__global__ void cast_dt(const float* __restrict__ dbc,
                        unsigned short* __restrict__ dst) {
  int i = blockIdx.x * 256 + threadIdx.x;   // over 2048*128
  int m = i >> 7, r = i & 127;
  dst[i] = f2bf(dbc[(size_t)m * 256 + r]);
}

// ---------------- bf16 MFMA GEMM: C[M][N] = A[M][K] * B[N][K]^T ----------------
// m97-style: 128x128 tile, BK=32, 256 threads (4 waves 2x2, each 64x64),
// global_load_lds width-16 staging, 16x16x32 bf16 MFMA, fp32 accum.
// Optional epilogue: C = softplus(acc + bias[n]) when bias_sp != nullptr.
#define BM 128
#define BN 128
#define BKK 32

__device__ __forceinline__ void stage_tile(const unsigned short* __restrict__ G,
                                           int ldK, int g0, int k0,
                                           unsigned short* lds, int wave, int lane) {
#pragma unroll
  for (int c = 0; c < 2; ++c) {
    // LDS dest is wave-uniform base + lane*16 (HW-defined): byte off =
    // c*4096 + wave*1024 + lane*16  ->  row = c*64 + wave*16 + lane/4, col8 = lane%4
    int row = c * 64 + wave * 16 + (lane >> 2);
    int col = (lane & 3) * 8;
    const unsigned short* src = G + (size_t)(g0 + row) * ldK + (k0 + col);
    unsigned short* dst = lds + c * 2048 + wave * 512;  // ushort units
    __builtin_amdgcn_global_load_lds((__attribute__((address_space(1))) void*)(src),
                                     (__attribute__((address_space(3))) void*)(dst),
                                     16, 0, 0);
  }
}

__global__ __launch_bounds__(256)
void gemm_bt(const unsigned short* __restrict__ A, const unsigned short* __restrict__ B,
             float* __restrict__ C, int M, int N, int K,
             const float* __restrict__ bias_sp) {
  __shared__ unsigned short As[BM * BKK];
  __shared__ unsigned short Bs[BN * BKK];
  const int tid = threadIdx.x;
  const int wave = tid >> 6, lane = tid & 63;
  const int wr = wave >> 1, wc = wave & 1;   // 2x2 waves, each owns 64x64 output
  const int m0 = blockIdx.y * BM, n0 = blockIdx.x * BN;
  const int lr = lane & 15, lg = lane >> 4;

  f32x4 zero = {0.f, 0.f, 0.f, 0.f};
  f32x4 acc[4][4];
#pragma unroll
  for (int i = 0; i < 4; ++i)
#pragma unroll
    for (int j = 0; j < 4; ++j) acc[i][j] = zero;

  for (int k0 = 0; k0 < K; k0 += BKK) {
    stage_tile(A, K, m0, k0, As, wave, lane);
    stage_tile(B, K, n0, k0, Bs, wave, lane);
    __syncthreads();   // drains vmcnt (global_load_lds) + lgkm
    bf16x8 af[4], bfr[4];
#pragma unroll
    for (int i = 0; i < 4; ++i)
      af[i] = *reinterpret_cast<const bf16x8*>(&As[(wr * 64 + i * 16 + lr) * BKK + lg * 8]);
#pragma unroll
    for (int j = 0; j < 4; ++j)
      bfr[j] = *reinterpret_cast<const bf16x8*>(&Bs[(wc * 64 + j * 16 + lr) * BKK + lg * 8]);
#pragma unroll
    for (int i = 0; i < 4; ++i)
#pragma unroll
      for (int j = 0; j < 4; ++j)
        acc[i][j] = __builtin_amdgcn_mfma_f32_16x16x32_bf16(af[i], bfr[j], acc[i][j], 0, 0, 0);
    __syncthreads();
  }

  // C/D layout (m89-verified): col = lane&15, row = (lane>>4)*4 + reg
#pragma unroll
  for (int i = 0; i < 4; ++i) {
#pragma unroll
    for (int j = 0; j < 4; ++j) {
      int mrow = m0 + wr * 64 + i * 16 + lg * 4;
      int ncol = n0 + wc * 64 + j * 16 + lr;
      if (bias_sp) {
        float bv = bias_sp[ncol];
#pragma unroll
        for (int r = 0; r < 4; ++r)
          C[(size_t)(mrow + r) * N + ncol] = softplus_f(acc[i][j][r] + bv);
      } else {
#pragma unroll
        for (int r = 0; r < 4; ++r)
          C[(size_t)(mrow + r) * N + ncol] = acc[i][j][r];
      }
    }
  }
}

// ---------------- conv(4, causal, depthwise) + silu ----------------
// xz: [2048][8192] fp32, xp = cols [0,4096). Writes xc fp32 + xc bf16.
__global__ void conv_silu_kernel(const float* __restrict__ xz,
                                 const float* __restrict__ conv_w,
                                 const float* __restrict__ conv_b,
                                 float* __restrict__ xc,
                                 unsigned short* __restrict__ xc_bf) {
  int idx = blockIdx.x * 256 + threadIdx.x;  // over 2048*4096
  int e = idx & 4095;
  int m = idx >> 12;
  int l = m & 1023;                          // within-batch position
  float acc = conv_b[e];
#pragma unroll
  for (int k = 0; k < 4; ++k) {
    int ls = l - 3 + k;
    if (ls >= 0) acc = fmaf(xz[(size_t)(m - 3 + k) * 8192 + e], conv_w[e * 4 + k], acc);
  }
  float s = silu_f(acc);
  xc[idx] = s;
  xc_bf[idx] = f2bf(s);
}

// ---------------- SSM scan: chunked 2-pass ----------------
// 16 chunks of 64 steps per batch. Pass1: per-chunk local scan from h=0,
// emit h_final[16] and P[16]=prod(dA). Pass2: sequential carry combine
// (in-place: hfin[c] <- carry-in of chunk c). Pass3: rescan with carry,
// produce y (bf16) with fused D-skip + silu(z) gate.
// Grid pass1/3: blockIdx = (b*16+c)*16 + eg; 256 threads over e.

__global__ __launch_bounds__(256)
void scan_pass1(const float* __restrict__ delta, const float* __restrict__ dbc,
                const float* __restrict__ xc, const float* __restrict__ A_log,
                float* __restrict__ hfin, float* __restrict__ Pprod) {
  __shared__ float Bsh[1024];           // [64][16]
  const int tid = threadIdx.x;
  const int bc = blockIdx.x >> 4;       // b*16 + c
  const int eg = blockIdx.x & 15;
  const int b = bc >> 4, c = bc & 15;
  const int e = eg * 256 + tid;
  const int mb = b * 1024 + c * 64;
  for (int i = tid; i < 1024; i += 256)
    Bsh[i] = dbc[(size_t)(mb + (i >> 4)) * 256 + 128 + (i & 15)];
  __syncthreads();

  float A[16];
  const float4* al = reinterpret_cast<const float4*>(A_log + (size_t)e * 16);
#pragma unroll
  for (int q = 0; q < 4; ++q) {
    float4 v = al[q];
    A[q * 4 + 0] = -__expf(v.x); A[q * 4 + 1] = -__expf(v.y);
    A[q * 4 + 2] = -__expf(v.z); A[q * 4 + 3] = -__expf(v.w);
  }
  float h[16], P[16];
#pragma unroll
  for (int s = 0; s < 16; ++s) { h[s] = 0.f; P[s] = 1.f; }

  for (int ll = 0; ll < 64; ++ll) {
    const size_t m = (size_t)(mb + ll);
    float dl = delta[m * 4096 + e];
    float dxc = dl * xc[m * 4096 + e];
#pragma unroll
    for (int s = 0; s < 16; ++s) {
      float dA = __expf(dl * A[s]);
      P[s] *= dA;
      h[s] = fmaf(dA, h[s], Bsh[ll * 16 + s] * dxc);
    }
  }
  float* hp = hfin + ((size_t)bc * 4096 + e) * 16;
  float* pp = Pprod + ((size_t)bc * 4096 + e) * 16;
#pragma unroll
  for (int s = 0; s < 16; ++s) { hp[s] = h[s]; pp[s] = P[s]; }
}

__global__ void scan_pass2(float* __restrict__ hfin, const float* __restrict__ Pprod) {
  int idx = blockIdx.x * 256 + threadIdx.x;   // 2*4096*16 = 131072
  int b = idx >> 16;
  int es = idx & 65535;                       // e*16 + s
  float H = 0.f;
  for (int c = 0; c < 16; ++c) {
    size_t o = ((size_t)(b * 16 + c) << 16) + es;
    float hf = hfin[o];
    float Pp = Pprod[o];
    hfin[o] = H;                              // carry-in for chunk c
    H = fmaf(Pp, H, hf);
  }
}

__global__ __launch_bounds__(256)
void scan_pass3(const float* __restrict__ delta, const float* __restrict__ dbc,
                const float* __restrict__ xc, const float* __restrict__ xz,
                const float* __restrict__ A_log, const float* __restrict__ Dp,
                const float* __restrict__ hcarry, unsigned short* __restrict__ y_bf) {
  __shared__ float Bsh[1024];           // [64][16]
  __shared__ float Csh[1024];
  const int tid = threadIdx.x;
  const int bc = blockIdx.x >> 4;
  const int eg = blockIdx.x & 15;
  const int b = bc >> 4, c = bc & 15;
  const int e = eg * 256 + tid;
  const int mb = b * 1024 + c * 64;
  for (int i = tid; i < 1024; i += 256) {
    size_t base = (size_t)(mb + (i >> 4)) * 256 + (i & 15);
    Bsh[i] = dbc[base + 128];
    Csh[i] = dbc[base + 144];
  }
  __syncthreads();

  float A[16];
  const float4* al = reinterpret_cast<const float4*>(A_log + (size_t)e * 16);
#pragma unroll
  for (int q = 0; q < 4; ++q) {
    float4 v = al[q];
    A[q * 4 + 0] = -__expf(v.x); A[q * 4 + 1] = -__expf(v.y);
    A[q * 4 + 2] = -__expf(v.z); A[q * 4 + 3] = -__expf(v.w);
  }
  float h[16];
  const float* hp = hcarry + ((size_t)bc * 4096 + e) * 16;
#pragma unroll
  for (int s = 0; s < 16; ++s) h[s] = hp[s];
  const float Dv = Dp[e];

  for (int ll = 0; ll < 64; ++ll) {
    const size_t m = (size_t)(mb + ll);
    float dl = delta[m * 4096 + e];
    float xcv = xc[m * 4096 + e];
    float dxc = dl * xcv;
    float y = 0.f;
#pragma unroll
    for (int s = 0; s < 16; ++s) {
      float dA = __expf(dl * A[s]);
      h[s] = fmaf(dA, h[s], Bsh[ll * 16 + s] * dxc);
      y = fmaf(h[s], Csh[ll * 16 + s], y);
    }
    float z = xz[m * 8192 + 4096 + e];
    y = (y + xcv * Dv) * silu_f(z);
    y_bf[m * 4096 + e] = f2bf(y);
  }
}

// ---------------------------------------------------------------------------
extern "C" void kernel_launch(void* const* d_in, const int* in_sizes, int n_in,
                              void* d_out, int out_size, void* d_ws, size_t ws_size,
                              hipStream_t stream) {
  const float* x      = (const float*)d_in[0];
  const float* W_in   = (const float*)d_in[1];
  const float* conv_w = (const float*)d_in[2];
  const float* conv_b = (const float*)d_in[3];
  const float* W_x    = (const float*)d_in[4];
  const float* W_dt   = (const float*)d_in[5];
  const float* b_dt   = (const float*)d_in[6];
  const float* A_log  = (const float*)d_in[7];
  const float* Dp     = (const float*)d_in[8];
  const float* W_out  = (const float*)d_in[9];
  float* out = (float*)d_out;
  char* ws = (char*)d_ws;

  // workspace layout (190,316,544 bytes; time-disjoint aliases marked)
  unsigned short* Win_bf    = (unsigned short*)(ws + 0);          // 33.55 MB
  float*          delta     = (float*)(ws + 0);                   // alias (after GEMM1)
  unsigned short* x_bf      = (unsigned short*)(ws + 33554432);   // 8.39 MB used
  unsigned short* y_bf      = (unsigned short*)(ws + 33554432);   // alias (after GEMM1)
  unsigned short* Wout_bf   = (unsigned short*)(ws + 50331648);   // 16.78 MB
  unsigned short* Wx_bf     = (unsigned short*)(ws + 67108864);   // 2.10 MB (padded 256 rows)
  unsigned short* Wdt_bf    = (unsigned short*)(ws + 69206016);   // 1.05 MB
  float*          xz        = (float*)(ws + 70254592);            // 67.11 MB
  float*          xc        = (float*)(ws + 137363456);           // 33.55 MB
  unsigned short* xc_bf     = (unsigned short*)(ws + 170917888);  // 16.78 MB (dead after GEMM2)
  float*          hfin      = (float*)(ws + 170917888);           // alias: 8.39 MB (chunk states)
  float*          Pprod     = (float*)(ws + 179306496);           // alias: 8.39 MB (chunk dA-products)
  float*          dbc       = (float*)(ws + 187695104);           // 2.10 MB ([2048][256], cols 160+ = 0)
  unsigned short* dt_bf     = (unsigned short*)(ws + 189792256);  // 0.52 MB

  // casts (bf16 operands for MFMA GEMMs)
  cast_f32_to_bf16<<<4096, 256, 0, stream>>>(x, x_bf, 1048576);
  cast_f32_to_bf16<<<16384, 256, 0, stream>>>(W_in, Win_bf, 4194304);
  cast_f32_to_bf16<<<8192, 256, 0, stream>>>(W_out, Wout_bf, 2097152);
  cast_wx_pad<<<4096, 256, 0, stream>>>(W_x, Wx_bf);
  cast_f32_to_bf16<<<512, 256, 0, stream>>>(W_dt, Wdt_bf, 131072);

  // GEMM1: xz[2048][8192] = x[2048][2048] @ W_in[8192][2048]^T
  gemm_bt<<<dim3(64, 16), 256, 0, stream>>>(x_bf, Win_bf, xz, 2048, 8192, 2048, nullptr);

  // conv + silu -> xc (fp32 + bf16)
  conv_silu_kernel<<<32768, 256, 0, stream>>>(xz, conv_w, conv_b, xc, xc_bf);

  // GEMM2: dbc[2048][256] = xc[2048][4096] @ Wx_pad[256][4096]^T
  gemm_bt<<<dim3(2, 16), 256, 0, stream>>>(xc_bf, Wx_bf, dbc, 2048, 256, 4096, nullptr);

  // dt -> bf16
  cast_dt<<<1024, 256, 0, stream>>>(dbc, dt_bf);

  // GEMM3 (+fused bias+softplus): delta[2048][4096] = sp(dt @ W_dt^T + b_dt)
  gemm_bt<<<dim3(32, 16), 256, 0, stream>>>(dt_bf, Wdt_bf, delta, 2048, 4096, 128, b_dt);

  // SSM scan: chunked two-pass
  scan_pass1<<<512, 256, 0, stream>>>(delta, dbc, xc, A_log, hfin, Pprod);
  scan_pass2<<<512, 256, 0, stream>>>(hfin, Pprod);
  scan_pass3<<<512, 256, 0, stream>>>(delta, dbc, xc, xz, A_log, Dp, hfin, y_bf);

  // GEMM4: out[2048][2048] = y[2048][4096] @ W_out[2048][4096]^T
  gemm_bt<<<dim3(16, 16), 256, 0, stream>>>(y_bf, Wout_bf, out, 2048, 2048, 4096, nullptr);
}

// Round 4
// 475.060 us; speedup vs baseline: 2.9030x; 1.0450x over previous
//
#include <hip/hip_runtime.h>
#include <cstdint>

// ---------------------------------------------------------------------------
// Mamba block: xz=x@W_in^T -> split(xp,z) -> causal depthwise conv4+silu ->
// dbc=xc@W_x^T -> split(dt,B,C) -> delta=softplus(dt@W_dt^T+b_dt) ->
// diagonal SSM scan (chunked, 2-pass) -> y=(sum_s h*C + xc*D)*silu(z) ->
// out=y@W_out^T
// Shapes: B=2,L=1024 (M=2048), D_MODEL=2048, D_INNER=4096, D_STATE=16,
// DT_RANK=128, D_CONV=4. Chunks: 16 per batch, 64 steps each.
// GEMM1 uses a 256^2-tile 8-wave deep-pipelined kernel (T2+T3+T4+T5);
// GEMM2/3/4 use the m97-style 128^2 kernel.
// ---------------------------------------------------------------------------

typedef __bf16 bf16x8 __attribute__((ext_vector_type(8)));
typedef float f32x4 __attribute__((ext_vector_type(4)));

__device__ __forceinline__ unsigned short f2bf(float f) {
  uint32_t u = __float_as_uint(f);
  u += 0x7FFFu + ((u >> 16) & 1u);   // round-to-nearest-even
  return (unsigned short)(u >> 16);
}

__device__ __forceinline__ float silu_f(float v) {
  return v / (1.f + __expf(-v));
}

__device__ __forceinline__ float softplus_f(float v) {
  return (v > 20.f) ? v : log1pf(__expf(v));
}

// ---------------- cast kernels ----------------
__global__ void cast_f32_to_bf16(const float* __restrict__ src,
                                 unsigned short* __restrict__ dst, int n4) {
  int i = blockIdx.x * 256 + threadIdx.x;
  if (i >= n4) return;
  float4 v = reinterpret_cast<const float4*>(src)[i];
  ushort4 o;
  o.x = f2bf(v.x); o.y = f2bf(v.y); o.z = f2bf(v.z); o.w = f2bf(v.w);
  reinterpret_cast<ushort4*>(dst)[i] = o;
}

// W_x is [160][4096]; pad to [256][4096] with zero rows so GEMM2 needs no guards.
__global__ void cast_wx_pad(const float* __restrict__ Wx,
                            unsigned short* __restrict__ dst) {
  int i = blockIdx.x * 256 + threadIdx.x;   // over 256*4096
  int r = i >> 12;
  float v = (r < 160) ? Wx[(size_t)r * 4096 + (i & 4095)] : 0.f;
  dst[i] = f2bf(v);
}

// dt = dbc[:, 0:128] -> bf16 [2048][128]
__global__ void cast_dt(const float* __restrict__ dbc,
                        unsigned short* __restrict__ dst) {
  int i = blockIdx.x * 256 + threadIdx.x;   // over 2048*128
  int m = i >> 7, r = i & 127;
  dst[i] = f2bf(dbc[(size_t)m * 256 + r]);
}

// ---------------- m97-style bf16 MFMA GEMM (128^2, BK=32) ----------------
#define BM 128
#define BN 128
#define BKK 32

__device__ __forceinline__ void stage_tile(const unsigned short* __restrict__ G,
                                           int ldK, int g0, int k0,
                                           unsigned short* lds, int wave, int lane) {
#pragma unroll
  for (int c = 0; c < 2; ++c) {
    int row = c * 64 + wave * 16 + (lane >> 2);
    int col = (lane & 3) * 8;
    const unsigned short* src = G + (size_t)(g0 + row) * ldK + (k0 + col);
    unsigned short* dst = lds + c * 2048 + wave * 512;  // ushort units
    __builtin_amdgcn_global_load_lds((__attribute__((address_space(1))) void*)(src),
                                     (__attribute__((address_space(3))) void*)(dst),
                                     16, 0, 0);
  }
}

__global__ __launch_bounds__(256)
void gemm_bt(const unsigned short* __restrict__ A, const unsigned short* __restrict__ B,
             float* __restrict__ C, int M, int N, int K,
             const float* __restrict__ bias_sp) {
  __shared__ unsigned short As[BM * BKK];
  __shared__ unsigned short Bs[BN * BKK];
  const int tid = threadIdx.x;
  const int wave = tid >> 6, lane = tid & 63;
  const int wr = wave >> 1, wc = wave & 1;   // 2x2 waves, each owns 64x64 output
  const int m0 = blockIdx.y * BM, n0 = blockIdx.x * BN;
  const int lr = lane & 15, lg = lane >> 4;

  f32x4 zero = {0.f, 0.f, 0.f, 0.f};
  f32x4 acc[4][4];
#pragma unroll
  for (int i = 0; i < 4; ++i)
#pragma unroll
    for (int j = 0; j < 4; ++j) acc[i][j] = zero;

  for (int k0 = 0; k0 < K; k0 += BKK) {
    stage_tile(A, K, m0, k0, As, wave, lane);
    stage_tile(B, K, n0, k0, Bs, wave, lane);
    __syncthreads();   // drains vmcnt (global_load_lds) + lgkm
    bf16x8 af[4], bfr[4];
#pragma unroll
    for (int i = 0; i < 4; ++i)
      af[i] = *reinterpret_cast<const bf16x8*>(&As[(wr * 64 + i * 16 + lr) * BKK + lg * 8]);
#pragma unroll
    for (int j = 0; j < 4; ++j)
      bfr[j] = *reinterpret_cast<const bf16x8*>(&Bs[(wc * 64 + j * 16 + lr) * BKK + lg * 8]);
#pragma unroll
    for (int i = 0; i < 4; ++i)
#pragma unroll
      for (int j = 0; j < 4; ++j)
        acc[i][j] = __builtin_amdgcn_mfma_f32_16x16x32_bf16(af[i], bfr[j], acc[i][j], 0, 0, 0);
    __syncthreads();
  }

  // C/D layout (m89-verified): col = lane&15, row = (lane>>4)*4 + reg
#pragma unroll
  for (int i = 0; i < 4; ++i) {
#pragma unroll
    for (int j = 0; j < 4; ++j) {
      int mrow = m0 + wr * 64 + i * 16 + lg * 4;
      int ncol = n0 + wc * 64 + j * 16 + lr;
      if (bias_sp) {
        float bv = bias_sp[ncol];
#pragma unroll
        for (int r = 0; r < 4; ++r)
          C[(size_t)(mrow + r) * N + ncol] = softplus_f(acc[i][j][r] + bv);
      } else {
#pragma unroll
        for (int r = 0; r < 4; ++r)
          C[(size_t)(mrow + r) * N + ncol] = acc[i][j][r];
      }
    }
  }
}

// ---------------- 256^2-tile 8-wave deep-pipelined GEMM (T2+T3+T4+T5) ------
// C[M][N] = A[M][K]*B[N][K]^T. 512 threads = 8 waves (2M x 4N), per-wave
// 128x64 output. BK=32 per K-tile, 2 LDS buffers (64KB total, static).
// Schedule per iteration (2 tiles): [vmcnt(4); bar] PHASE(buf0) [bar]
// STAGE(t+2) [vmcnt(4); bar] PHASE(buf1) [bar] STAGE(t+3).
// Buffers are proven dead (barrier) before their refill is issued; counted
// vmcnt keeps prefetch in flight across barriers (never 0 mid-loop).
// T2 swizzle: LDS phys_ushort = logical ^ ((row>>1)&3)<<3, realized as
// linear global_load_lds dest + inverse-swizzled global source column,
// XOR applied on the ds_read side. Requires M%256==0, N%256==0, K%64==0.
__global__ __launch_bounds__(512, 2)
void gemm_bt_8ph(const unsigned short* __restrict__ A,
                 const unsigned short* __restrict__ B,
                 float* __restrict__ C, int M, int N, int K, int nbm) {
  __shared__ unsigned short As[2][8192];   // [buf][256 rows * 32 cols]
  __shared__ unsigned short Bs[2][8192];
  const int tid = threadIdx.x;
  const int wid = tid >> 6, lane = tid & 63;
  const int wr = wid >> 2, wc = wid & 3;     // 2 x 4 waves
  const int lr = lane & 15, lg = lane >> 4;

  // XCD-bijective swizzle (gridDim.x % 8 == 0), bm-fast linearization
  const int cpx = gridDim.x >> 3;
  const int x = blockIdx.x;
  const int wg = (x & 7) * cpx + (x >> 3);
  const int bm = wg % nbm, bn = wg / nbm;
  const int m0 = bm * 256, n0 = bn * 256;

  // Staging geometry: tile = 16 segments of 16 rows; wave w stages segs
  // {2w, 2w+1} for A and B. Lane l covers row l>>2, dest col (l&3)*8;
  // source col is inverse-swizzled.
  const int srow = lane >> 2;
  const int scol = ((lane & 3) * 8) ^ (((lane >> 3) & 3) << 3);
  const unsigned short* Abase = A + (size_t)(m0 + wid * 32 + srow) * K + scol;
  const unsigned short* Bbase = B + (size_t)(n0 + wid * 32 + srow) * K + scol;

  // Read-side swizzled fragment offsets (ushort units)
  const int swz = ((lr >> 1) & 3) << 3;
  const int aoff = (((wr * 128 + lr) * 32) + lg * 8) ^ swz;
  const int boff = (((wc * 64 + lr) * 32) + lg * 8) ^ swz;

  f32x4 acc[8][4];
  f32x4 zero = {0.f, 0.f, 0.f, 0.f};
#pragma unroll
  for (int i = 0; i < 8; ++i)
#pragma unroll
    for (int j = 0; j < 4; ++j) acc[i][j] = zero;

  const int nt = K / 32;   // must be even, >= 2

  auto STAGE = [&](int t) {
    const int buf = t & 1;
    const unsigned short* ap = Abase + t * 32;
    const unsigned short* bp = Bbase + t * 32;
#pragma unroll
    for (int c = 0; c < 2; ++c) {
      __builtin_amdgcn_global_load_lds(
          (__attribute__((address_space(1))) const void*)(ap + (size_t)c * 16 * K),
          (__attribute__((address_space(3))) void*)(&As[buf][wid * 1024 + c * 512]),
          16, 0, 0);
      __builtin_amdgcn_global_load_lds(
          (__attribute__((address_space(1))) const void*)(bp + (size_t)c * 16 * K),
          (__attribute__((address_space(3))) void*)(&Bs[buf][wid * 1024 + c * 512]),
          16, 0, 0);
    }
  };

  auto PHASE = [&](int buf) {
    bf16x8 a[8], b[4];
#pragma unroll
    for (int mf = 0; mf < 8; ++mf)
      a[mf] = *reinterpret_cast<const bf16x8*>(&As[buf][aoff + mf * 512]);
#pragma unroll
    for (int nf = 0; nf < 4; ++nf)
      b[nf] = *reinterpret_cast<const bf16x8*>(&Bs[buf][boff + nf * 512]);
    asm volatile("s_waitcnt lgkmcnt(0)" ::: "memory");
    __builtin_amdgcn_sched_barrier(0);
    __builtin_amdgcn_s_setprio(1);
#pragma unroll
    for (int nf = 0; nf < 4; ++nf)
#pragma unroll
      for (int mf = 0; mf < 8; ++mf)
        acc[mf][nf] = __builtin_amdgcn_mfma_f32_16x16x32_bf16(a[mf], b[nf], acc[mf][nf], 0, 0, 0);
    __builtin_amdgcn_s_setprio(0);
  };

  STAGE(0);
  STAGE(1);
  for (int t = 0; t < nt; t += 2) {
    // tile t ready: all but the newest 4 loads (= stage(t+1)) complete
    asm volatile("s_waitcnt vmcnt(4)" ::: "memory");
    __builtin_amdgcn_s_barrier();
    PHASE(0);                              // tile t (even -> buf0)
    __builtin_amdgcn_s_barrier();          // buf0 dead across all waves
    if (t + 2 < nt) {
      STAGE(t + 2);                        // refill buf0
      asm volatile("s_waitcnt vmcnt(4)" ::: "memory");   // tile t+1 ready
    } else {
      asm volatile("s_waitcnt vmcnt(0)" ::: "memory");   // tail: drain
    }
    __builtin_amdgcn_s_barrier();
    PHASE(1);                              // tile t+1 (buf1)
    __builtin_amdgcn_s_barrier();          // buf1 dead
    if (t + 3 < nt) STAGE(t + 3);          // refill buf1
  }

  // Epilogue: C/D layout col=lane&15, row=(lane>>4)*4+reg (m89-verified)
#pragma unroll
  for (int mf = 0; mf < 8; ++mf) {
#pragma unroll
    for (int nf = 0; nf < 4; ++nf) {
      int mrow = m0 + wr * 128 + mf * 16 + lg * 4;
      int ncol = n0 + wc * 64 + nf * 16 + lr;
#pragma unroll
      for (int r = 0; r < 4; ++r)
        C[(size_t)(mrow + r) * N + ncol] = acc[mf][nf][r];
    }
  }
}

// ---------------- conv(4, causal, depthwise) + silu ----------------
__global__ void conv_silu_kernel(const float* __restrict__ xz,
                                 const float* __restrict__ conv_w,
                                 const float* __restrict__ conv_b,
                                 float* __restrict__ xc,
                                 unsigned short* __restrict__ xc_bf) {
  int idx = blockIdx.x * 256 + threadIdx.x;  // over 2048*4096
  int e = idx & 4095;
  int m = idx >> 12;
  int l = m & 1023;                          // within-batch position
  float acc = conv_b[e];
#pragma unroll
  for (int k = 0; k < 4; ++k) {
    int ls = l - 3 + k;
    if (ls >= 0) acc = fmaf(xz[(size_t)(m - 3 + k) * 8192 + e], conv_w[e * 4 + k], acc);
  }
  float s = silu_f(acc);
  xc[idx] = s;
  xc_bf[idx] = f2bf(s);
}

// ---------------- SSM scan: chunked 2-pass ----------------
__global__ __launch_bounds__(256)
void scan_pass1(const float* __restrict__ delta, const float* __restrict__ dbc,
                const float* __restrict__ xc, const float* __restrict__ A_log,
                float* __restrict__ hfin, float* __restrict__ Pprod) {
  __shared__ float Bsh[1024];           // [64][16]
  const int tid = threadIdx.x;
  const int bc = blockIdx.x >> 4;       // b*16 + c
  const int eg = blockIdx.x & 15;
  const int b = bc >> 4, c = bc & 15;
  const int e = eg * 256 + tid;
  const int mb = b * 1024 + c * 64;
  for (int i = tid; i < 1024; i += 256)
    Bsh[i] = dbc[(size_t)(mb + (i >> 4)) * 256 + 128 + (i & 15)];
  __syncthreads();

  float A[16];
  const float4* al = reinterpret_cast<const float4*>(A_log + (size_t)e * 16);
#pragma unroll
  for (int q = 0; q < 4; ++q) {
    float4 v = al[q];
    A[q * 4 + 0] = -__expf(v.x); A[q * 4 + 1] = -__expf(v.y);
    A[q * 4 + 2] = -__expf(v.z); A[q * 4 + 3] = -__expf(v.w);
  }
  float h[16], P[16];
#pragma unroll
  for (int s = 0; s < 16; ++s) { h[s] = 0.f; P[s] = 1.f; }

  for (int ll = 0; ll < 64; ++ll) {
    const size_t m = (size_t)(mb + ll);
    float dl = delta[m * 4096 + e];
    float dxc = dl * xc[m * 4096 + e];
#pragma unroll
    for (int s = 0; s < 16; ++s) {
      float dA = __expf(dl * A[s]);
      P[s] *= dA;
      h[s] = fmaf(dA, h[s], Bsh[ll * 16 + s] * dxc);
    }
  }
  float* hp = hfin + ((size_t)bc * 4096 + e) * 16;
  float* pp = Pprod + ((size_t)bc * 4096 + e) * 16;
#pragma unroll
  for (int s = 0; s < 16; ++s) { hp[s] = h[s]; pp[s] = P[s]; }
}

__global__ void scan_pass2(float* __restrict__ hfin, const float* __restrict__ Pprod) {
  int idx = blockIdx.x * 256 + threadIdx.x;   // 2*4096*16 = 131072
  int b = idx >> 16;
  int es = idx & 65535;                       // e*16 + s
  float H = 0.f;
  for (int c = 0; c < 16; ++c) {
    size_t o = ((size_t)(b * 16 + c) << 16) + es;
    float hf = hfin[o];
    float Pp = Pprod[o];
    hfin[o] = H;                              // carry-in for chunk c
    H = fmaf(Pp, H, hf);
  }
}

__global__ __launch_bounds__(256)
void scan_pass3(const float* __restrict__ delta, const float* __restrict__ dbc,
                const float* __restrict__ xc, const float* __restrict__ xz,
                const float* __restrict__ A_log, const float* __restrict__ Dp,
                const float* __restrict__ hcarry, unsigned short* __restrict__ y_bf) {
  __shared__ float Bsh[1024];           // [64][16]
  __shared__ float Csh[1024];
  const int tid = threadIdx.x;
  const int bc = blockIdx.x >> 4;
  const int eg = blockIdx.x & 15;
  const int b = bc >> 4, c = bc & 15;
  const int e = eg * 256 + tid;
  const int mb = b * 1024 + c * 64;
  for (int i = tid; i < 1024; i += 256) {
    size_t base = (size_t)(mb + (i >> 4)) * 256 + (i & 15);
    Bsh[i] = dbc[base + 128];
    Csh[i] = dbc[base + 144];
  }
  __syncthreads();

  float A[16];
  const float4* al = reinterpret_cast<const float4*>(A_log + (size_t)e * 16);
#pragma unroll
  for (int q = 0; q < 4; ++q) {
    float4 v = al[q];
    A[q * 4 + 0] = -__expf(v.x); A[q * 4 + 1] = -__expf(v.y);
    A[q * 4 + 2] = -__expf(v.z); A[q * 4 + 3] = -__expf(v.w);
  }
  float h[16];
  const float* hp = hcarry + ((size_t)bc * 4096 + e) * 16;
#pragma unroll
  for (int s = 0; s < 16; ++s) h[s] = hp[s];
  const float Dv = Dp[e];

  for (int ll = 0; ll < 64; ++ll) {
    const size_t m = (size_t)(mb + ll);
    float dl = delta[m * 4096 + e];
    float xcv = xc[m * 4096 + e];
    float dxc = dl * xcv;
    float y = 0.f;
#pragma unroll
    for (int s = 0; s < 16; ++s) {
      float dA = __expf(dl * A[s]);
      h[s] = fmaf(dA, h[s], Bsh[ll * 16 + s] * dxc);
      y = fmaf(h[s], Csh[ll * 16 + s], y);
    }
    float z = xz[m * 8192 + 4096 + e];
    y = (y + xcv * Dv) * silu_f(z);
    y_bf[m * 4096 + e] = f2bf(y);
  }
}

// ---------------------------------------------------------------------------
extern "C" void kernel_launch(void* const* d_in, const int* in_sizes, int n_in,
                              void* d_out, int out_size, void* d_ws, size_t ws_size,
                              hipStream_t stream) {
  const float* x      = (const float*)d_in[0];
  const float* W_in   = (const float*)d_in[1];
  const float* conv_w = (const float*)d_in[2];
  const float* conv_b = (const float*)d_in[3];
  const float* W_x    = (const float*)d_in[4];
  const float* W_dt   = (const float*)d_in[5];
  const float* b_dt   = (const float*)d_in[6];
  const float* A_log  = (const float*)d_in[7];
  const float* Dp     = (const float*)d_in[8];
  const float* W_out  = (const float*)d_in[9];
  float* out = (float*)d_out;
  char* ws = (char*)d_ws;

  // workspace layout (190,316,544 bytes; time-disjoint aliases marked)
  unsigned short* Win_bf    = (unsigned short*)(ws + 0);          // 33.55 MB
  float*          delta     = (float*)(ws + 0);                   // alias (after GEMM1)
  unsigned short* x_bf      = (unsigned short*)(ws + 33554432);   // 8.39 MB used
  unsigned short* y_bf      = (unsigned short*)(ws + 33554432);   // alias (after GEMM1)
  unsigned short* Wout_bf   = (unsigned short*)(ws + 50331648);   // 16.78 MB
  unsigned short* Wx_bf     = (unsigned short*)(ws + 67108864);   // 2.10 MB (padded 256 rows)
  unsigned short* Wdt_bf    = (unsigned short*)(ws + 69206016);   // 1.05 MB
  float*          xz        = (float*)(ws + 70254592);            // 67.11 MB
  float*          xc        = (float*)(ws + 137363456);           // 33.55 MB
  unsigned short* xc_bf     = (unsigned short*)(ws + 170917888);  // 16.78 MB (dead after GEMM2)
  float*          hfin      = (float*)(ws + 170917888);           // alias: 8.39 MB (chunk states)
  float*          Pprod     = (float*)(ws + 179306496);           // alias: 8.39 MB (chunk dA-products)
  float*          dbc       = (float*)(ws + 187695104);           // 2.10 MB ([2048][256], cols 160+ = 0)
  unsigned short* dt_bf     = (unsigned short*)(ws + 189792256);  // 0.52 MB

  // casts (bf16 operands for MFMA GEMMs)
  cast_f32_to_bf16<<<4096, 256, 0, stream>>>(x, x_bf, 1048576);
  cast_f32_to_bf16<<<16384, 256, 0, stream>>>(W_in, Win_bf, 4194304);
  cast_f32_to_bf16<<<8192, 256, 0, stream>>>(W_out, Wout_bf, 2097152);
  cast_wx_pad<<<4096, 256, 0, stream>>>(W_x, Wx_bf);
  cast_f32_to_bf16<<<512, 256, 0, stream>>>(W_dt, Wdt_bf, 131072);

  // GEMM1: xz[2048][8192] = x[2048][2048] @ W_in[8192][2048]^T  (8-phase 256^2)
  gemm_bt_8ph<<<256, 512, 0, stream>>>(x_bf, Win_bf, xz, 2048, 8192, 2048, 8);

  // conv + silu -> xc (fp32 + bf16)
  conv_silu_kernel<<<32768, 256, 0, stream>>>(xz, conv_w, conv_b, xc, xc_bf);

  // GEMM2: dbc[2048][256] = xc[2048][4096] @ Wx_pad[256][4096]^T
  gemm_bt<<<dim3(2, 16), 256, 0, stream>>>(xc_bf, Wx_bf, dbc, 2048, 256, 4096, nullptr);

  // dt -> bf16
  cast_dt<<<1024, 256, 0, stream>>>(dbc, dt_bf);

  // GEMM3 (+fused bias+softplus): delta[2048][4096] = sp(dt @ W_dt^T + b_dt)
  gemm_bt<<<dim3(32, 16), 256, 0, stream>>>(dt_bf, Wdt_bf, delta, 2048, 4096, 128, b_dt);

  // SSM scan: chunked two-pass
  scan_pass1<<<512, 256, 0, stream>>>(delta, dbc, xc, A_log, hfin, Pprod);
  scan_pass2<<<512, 256, 0, stream>>>(hfin, Pprod);
  scan_pass3<<<512, 256, 0, stream>>>(delta, dbc, xc, xz, A_log, Dp, hfin, y_bf);

  // GEMM4: out[2048][2048] = y[2048][4096] @ W_out[2048][4096]^T
  gemm_bt<<<dim3(16, 16), 256, 0, stream>>>(y_bf, Wout_bf, out, 2048, 2048, 4096, nullptr);
}

// Round 5
// 389.925 us; speedup vs baseline: 3.5368x; 1.2183x over previous
//
#include <hip/hip_runtime.h>
#include <cstdint>

// ---------------------------------------------------------------------------
// Mamba block: xz=x@W_in^T -> split(xp,z) -> causal depthwise conv4+silu ->
// dbc=xc@W_x^T -> split(dt,B,C) -> delta=softplus(dt@W_dt^T+b_dt) ->
// diagonal SSM scan (chunked, 2-pass) -> y=(sum_s h*C + xc*D)*silu(z) ->
// out=y@W_out^T
// Shapes: B=2,L=1024 (M=2048), D_MODEL=2048, D_INNER=4096, D_STATE=16,
// DT_RANK=128, D_CONV=4. Chunks: 16 per batch, 64 steps each.
// GEMM1: 256^2-tile 8-wave deep-pipelined kernel (T2+T3+T4+T5).
// GEMM2: m97 128^2 with split-K=8 (+fused reduce->dbc,dt_bf).
// GEMM3: m97 128^2, fused bias+softplus epilogue.
// GEMM4: m97 128^2 with split-K=2 (+float4 reduce). Split-K fixes the
// 1-block/CU occupancy starvation (Occ 10.8%, MfmaUtil 13.7% at R4).
// ---------------------------------------------------------------------------

typedef __bf16 bf16x8 __attribute__((ext_vector_type(8)));
typedef float f32x4 __attribute__((ext_vector_type(4)));

__device__ __forceinline__ unsigned short f2bf(float f) {
  uint32_t u = __float_as_uint(f);
  u += 0x7FFFu + ((u >> 16) & 1u);   // round-to-nearest-even
  return (unsigned short)(u >> 16);
}

__device__ __forceinline__ float silu_f(float v) {
  return v / (1.f + __expf(-v));
}

__device__ __forceinline__ float softplus_f(float v) {
  return (v > 20.f) ? v : log1pf(__expf(v));
}

// ---------------- cast kernels ----------------
__global__ void cast_f32_to_bf16(const float* __restrict__ src,
                                 unsigned short* __restrict__ dst, int n4) {
  int i = blockIdx.x * 256 + threadIdx.x;
  if (i >= n4) return;
  float4 v = reinterpret_cast<const float4*>(src)[i];
  ushort4 o;
  o.x = f2bf(v.x); o.y = f2bf(v.y); o.z = f2bf(v.z); o.w = f2bf(v.w);
  reinterpret_cast<ushort4*>(dst)[i] = o;
}

// W_x is [160][4096]; pad to [256][4096] with zero rows so GEMM2 needs no guards.
__global__ void cast_wx_pad(const float* __restrict__ Wx,
                            unsigned short* __restrict__ dst) {
  int i = blockIdx.x * 256 + threadIdx.x;   // over 256*4096
  int r = i >> 12;
  float v = (r < 160) ? Wx[(size_t)r * 4096 + (i & 4095)] : 0.f;
  dst[i] = f2bf(v);
}

// ---------------- m97-style bf16 MFMA GEMM (128^2, BK=32, split-K) --------
// C[M][N] (+ z*M*N) = A[M][ldK] rows m0.., cols [z*kchunk, (z+1)*kchunk) *
// B[N][ldK]^T. bias_sp: softplus(acc+bias[n]) epilogue (use only with
// gridDim.z==1).
#define BM 128
#define BN 128
#define BKK 32

__device__ __forceinline__ void stage_tile(const unsigned short* __restrict__ G,
                                           int ldK, int g0, int k0,
                                           unsigned short* lds, int wave, int lane) {
#pragma unroll
  for (int c = 0; c < 2; ++c) {
    int row = c * 64 + wave * 16 + (lane >> 2);
    int col = (lane & 3) * 8;
    const unsigned short* src = G + (size_t)(g0 + row) * ldK + (k0 + col);
    unsigned short* dst = lds + c * 2048 + wave * 512;  // ushort units
    __builtin_amdgcn_global_load_lds((__attribute__((address_space(1))) void*)(src),
                                     (__attribute__((address_space(3))) void*)(dst),
                                     16, 0, 0);
  }
}

__global__ __launch_bounds__(256)
void gemm_bt(const unsigned short* __restrict__ A, const unsigned short* __restrict__ B,
             float* __restrict__ C, int M, int N, int ldK, int kchunk,
             const float* __restrict__ bias_sp) {
  __shared__ unsigned short As[BM * BKK];
  __shared__ unsigned short Bs[BN * BKK];
  const int tid = threadIdx.x;
  const int wave = tid >> 6, lane = tid & 63;
  const int wr = wave >> 1, wc = wave & 1;   // 2x2 waves, each owns 64x64 output
  const int m0 = blockIdx.y * BM, n0 = blockIdx.x * BN;
  const int lr = lane & 15, lg = lane >> 4;
  const int kb = blockIdx.z * kchunk, ke = kb + kchunk;
  C += (size_t)blockIdx.z * M * N;

  f32x4 zero = {0.f, 0.f, 0.f, 0.f};
  f32x4 acc[4][4];
#pragma unroll
  for (int i = 0; i < 4; ++i)
#pragma unroll
    for (int j = 0; j < 4; ++j) acc[i][j] = zero;

  for (int k0 = kb; k0 < ke; k0 += BKK) {
    stage_tile(A, ldK, m0, k0, As, wave, lane);
    stage_tile(B, ldK, n0, k0, Bs, wave, lane);
    __syncthreads();   // drains vmcnt (global_load_lds) + lgkm
    bf16x8 af[4], bfr[4];
#pragma unroll
    for (int i = 0; i < 4; ++i)
      af[i] = *reinterpret_cast<const bf16x8*>(&As[(wr * 64 + i * 16 + lr) * BKK + lg * 8]);
#pragma unroll
    for (int j = 0; j < 4; ++j)
      bfr[j] = *reinterpret_cast<const bf16x8*>(&Bs[(wc * 64 + j * 16 + lr) * BKK + lg * 8]);
#pragma unroll
    for (int i = 0; i < 4; ++i)
#pragma unroll
      for (int j = 0; j < 4; ++j)
        acc[i][j] = __builtin_amdgcn_mfma_f32_16x16x32_bf16(af[i], bfr[j], acc[i][j], 0, 0, 0);
    __syncthreads();
  }

  // C/D layout (m89-verified): col = lane&15, row = (lane>>4)*4 + reg
#pragma unroll
  for (int i = 0; i < 4; ++i) {
#pragma unroll
    for (int j = 0; j < 4; ++j) {
      int mrow = m0 + wr * 64 + i * 16 + lg * 4;
      int ncol = n0 + wc * 64 + j * 16 + lr;
      if (bias_sp) {
        float bv = bias_sp[ncol];
#pragma unroll
        for (int r = 0; r < 4; ++r)
          C[(size_t)(mrow + r) * N + ncol] = softplus_f(acc[i][j][r] + bv);
      } else {
#pragma unroll
        for (int r = 0; r < 4; ++r)
          C[(size_t)(mrow + r) * N + ncol] = acc[i][j][r];
      }
    }
  }
}

// split-K reducers --------------------------------------------------------
// GEMM2: sum 8 planes of [2048][256]; write dbc fp32 + dt_bf (cols<128).
__global__ void reduce8_dbc(const float* __restrict__ p, float* __restrict__ dbc,
                            unsigned short* __restrict__ dt_bf) {
  int i = blockIdx.x * 256 + threadIdx.x;   // over 524288
  float s = 0.f;
#pragma unroll
  for (int c = 0; c < 8; ++c) s += p[(size_t)c * 524288 + i];
  dbc[i] = s;
  int col = i & 255;
  if (col < 128) dt_bf[(size_t)(i >> 8) * 128 + col] = f2bf(s);
}

// GEMM4: out = p0 + p1 over 2048x2048 (float4).
__global__ void reduce2_out(const float* __restrict__ p, float* __restrict__ out) {
  int i = blockIdx.x * 256 + threadIdx.x;   // over 1048576 float4s
  const float4* p4 = reinterpret_cast<const float4*>(p);
  float4 a = p4[i], b = p4[i + 1048576];
  float4 r; r.x = a.x + b.x; r.y = a.y + b.y; r.z = a.z + b.z; r.w = a.w + b.w;
  reinterpret_cast<float4*>(out)[i] = r;
}

// ---------------- 256^2-tile 8-wave deep-pipelined GEMM (T2+T3+T4+T5) ------
__global__ __launch_bounds__(512, 2)
void gemm_bt_8ph(const unsigned short* __restrict__ A,
                 const unsigned short* __restrict__ B,
                 float* __restrict__ C, int M, int N, int K, int nbm) {
  __shared__ unsigned short As[2][8192];   // [buf][256 rows * 32 cols]
  __shared__ unsigned short Bs[2][8192];
  const int tid = threadIdx.x;
  const int wid = tid >> 6, lane = tid & 63;
  const int wr = wid >> 2, wc = wid & 3;     // 2 x 4 waves
  const int lr = lane & 15, lg = lane >> 4;

  // XCD-bijective swizzle (gridDim.x % 8 == 0), bm-fast linearization
  const int cpx = gridDim.x >> 3;
  const int x = blockIdx.x;
  const int wg = (x & 7) * cpx + (x >> 3);
  const int bm = wg % nbm, bn = wg / nbm;
  const int m0 = bm * 256, n0 = bn * 256;

  const int srow = lane >> 2;
  const int scol = ((lane & 3) * 8) ^ (((lane >> 3) & 3) << 3);
  const unsigned short* Abase = A + (size_t)(m0 + wid * 32 + srow) * K + scol;
  const unsigned short* Bbase = B + (size_t)(n0 + wid * 32 + srow) * K + scol;

  const int swz = ((lr >> 1) & 3) << 3;
  const int aoff = (((wr * 128 + lr) * 32) + lg * 8) ^ swz;
  const int boff = (((wc * 64 + lr) * 32) + lg * 8) ^ swz;

  f32x4 acc[8][4];
  f32x4 zero = {0.f, 0.f, 0.f, 0.f};
#pragma unroll
  for (int i = 0; i < 8; ++i)
#pragma unroll
    for (int j = 0; j < 4; ++j) acc[i][j] = zero;

  const int nt = K / 32;   // must be even, >= 2

  auto STAGE = [&](int t) {
    const int buf = t & 1;
    const unsigned short* ap = Abase + t * 32;
    const unsigned short* bp = Bbase + t * 32;
#pragma unroll
    for (int c = 0; c < 2; ++c) {
      __builtin_amdgcn_global_load_lds(
          (__attribute__((address_space(1))) const void*)(ap + (size_t)c * 16 * K),
          (__attribute__((address_space(3))) void*)(&As[buf][wid * 1024 + c * 512]),
          16, 0, 0);
      __builtin_amdgcn_global_load_lds(
          (__attribute__((address_space(1))) const void*)(bp + (size_t)c * 16 * K),
          (__attribute__((address_space(3))) void*)(&Bs[buf][wid * 1024 + c * 512]),
          16, 0, 0);
    }
  };

  auto PHASE = [&](int buf) {
    bf16x8 a[8], b[4];
#pragma unroll
    for (int mf = 0; mf < 8; ++mf)
      a[mf] = *reinterpret_cast<const bf16x8*>(&As[buf][aoff + mf * 512]);
#pragma unroll
    for (int nf = 0; nf < 4; ++nf)
      b[nf] = *reinterpret_cast<const bf16x8*>(&Bs[buf][boff + nf * 512]);
    asm volatile("s_waitcnt lgkmcnt(0)" ::: "memory");
    __builtin_amdgcn_sched_barrier(0);
    __builtin_amdgcn_s_setprio(1);
#pragma unroll
    for (int nf = 0; nf < 4; ++nf)
#pragma unroll
      for (int mf = 0; mf < 8; ++mf)
        acc[mf][nf] = __builtin_amdgcn_mfma_f32_16x16x32_bf16(a[mf], b[nf], acc[mf][nf], 0, 0, 0);
    __builtin_amdgcn_s_setprio(0);
  };

  STAGE(0);
  STAGE(1);
  for (int t = 0; t < nt; t += 2) {
    asm volatile("s_waitcnt vmcnt(4)" ::: "memory");
    __builtin_amdgcn_s_barrier();
    PHASE(0);                              // tile t (even -> buf0)
    __builtin_amdgcn_s_barrier();          // buf0 dead across all waves
    if (t + 2 < nt) {
      STAGE(t + 2);                        // refill buf0
      asm volatile("s_waitcnt vmcnt(4)" ::: "memory");   // tile t+1 ready
    } else {
      asm volatile("s_waitcnt vmcnt(0)" ::: "memory");   // tail: drain
    }
    __builtin_amdgcn_s_barrier();
    PHASE(1);                              // tile t+1 (buf1)
    __builtin_amdgcn_s_barrier();          // buf1 dead
    if (t + 3 < nt) STAGE(t + 3);          // refill buf1
  }

  // Epilogue: C/D layout col=lane&15, row=(lane>>4)*4+reg (m89-verified)
#pragma unroll
  for (int mf = 0; mf < 8; ++mf) {
#pragma unroll
    for (int nf = 0; nf < 4; ++nf) {
      int mrow = m0 + wr * 128 + mf * 16 + lg * 4;
      int ncol = n0 + wc * 64 + nf * 16 + lr;
#pragma unroll
      for (int r = 0; r < 4; ++r)
        C[(size_t)(mrow + r) * N + ncol] = acc[mf][nf][r];
    }
  }
}

// ---------------- conv(4, causal, depthwise) + silu ----------------
__global__ void conv_silu_kernel(const float* __restrict__ xz,
                                 const float* __restrict__ conv_w,
                                 const float* __restrict__ conv_b,
                                 float* __restrict__ xc,
                                 unsigned short* __restrict__ xc_bf) {
  int idx = blockIdx.x * 256 + threadIdx.x;  // over 2048*4096
  int e = idx & 4095;
  int m = idx >> 12;
  int l = m & 1023;                          // within-batch position
  float acc = conv_b[e];
#pragma unroll
  for (int k = 0; k < 4; ++k) {
    int ls = l - 3 + k;
    if (ls >= 0) acc = fmaf(xz[(size_t)(m - 3 + k) * 8192 + e], conv_w[e * 4 + k], acc);
  }
  float s = silu_f(acc);
  xc[idx] = s;
  xc_bf[idx] = f2bf(s);
}

// ---------------- SSM scan: chunked 2-pass ----------------
__global__ __launch_bounds__(256)
void scan_pass1(const float* __restrict__ delta, const float* __restrict__ dbc,
                const float* __restrict__ xc, const float* __restrict__ A_log,
                float* __restrict__ hfin, float* __restrict__ Pprod) {
  __shared__ float Bsh[1024];           // [64][16]
  const int tid = threadIdx.x;
  const int bc = blockIdx.x >> 4;       // b*16 + c
  const int eg = blockIdx.x & 15;
  const int b = bc >> 4, c = bc & 15;
  const int e = eg * 256 + tid;
  const int mb = b * 1024 + c * 64;
  for (int i = tid; i < 1024; i += 256)
    Bsh[i] = dbc[(size_t)(mb + (i >> 4)) * 256 + 128 + (i & 15)];
  __syncthreads();

  float A[16];
  const float4* al = reinterpret_cast<const float4*>(A_log + (size_t)e * 16);
#pragma unroll
  for (int q = 0; q < 4; ++q) {
    float4 v = al[q];
    A[q * 4 + 0] = -__expf(v.x); A[q * 4 + 1] = -__expf(v.y);
    A[q * 4 + 2] = -__expf(v.z); A[q * 4 + 3] = -__expf(v.w);
  }
  float h[16], P[16];
#pragma unroll
  for (int s = 0; s < 16; ++s) { h[s] = 0.f; P[s] = 1.f; }

  for (int ll = 0; ll < 64; ++ll) {
    const size_t m = (size_t)(mb + ll);
    float dl = delta[m * 4096 + e];
    float dxc = dl * xc[m * 4096 + e];
#pragma unroll
    for (int s = 0; s < 16; ++s) {
      float dA = __expf(dl * A[s]);
      P[s] *= dA;
      h[s] = fmaf(dA, h[s], Bsh[ll * 16 + s] * dxc);
    }
  }
  float* hp = hfin + ((size_t)bc * 4096 + e) * 16;
  float* pp = Pprod + ((size_t)bc * 4096 + e) * 16;
#pragma unroll
  for (int s = 0; s < 16; ++s) { hp[s] = h[s]; pp[s] = P[s]; }
}

__global__ void scan_pass2(float* __restrict__ hfin, const float* __restrict__ Pprod) {
  int idx = blockIdx.x * 256 + threadIdx.x;   // 2*4096*16 = 131072
  int b = idx >> 16;
  int es = idx & 65535;                       // e*16 + s
  float H = 0.f;
  for (int c = 0; c < 16; ++c) {
    size_t o = ((size_t)(b * 16 + c) << 16) + es;
    float hf = hfin[o];
    float Pp = Pprod[o];
    hfin[o] = H;                              // carry-in for chunk c
    H = fmaf(Pp, H, hf);
  }
}

__global__ __launch_bounds__(256)
void scan_pass3(const float* __restrict__ delta, const float* __restrict__ dbc,
                const float* __restrict__ xc, const float* __restrict__ xz,
                const float* __restrict__ A_log, const float* __restrict__ Dp,
                const float* __restrict__ hcarry, unsigned short* __restrict__ y_bf) {
  __shared__ float Bsh[1024];           // [64][16]
  __shared__ float Csh[1024];
  const int tid = threadIdx.x;
  const int bc = blockIdx.x >> 4;
  const int eg = blockIdx.x & 15;
  const int b = bc >> 4, c = bc & 15;
  const int e = eg * 256 + tid;
  const int mb = b * 1024 + c * 64;
  for (int i = tid; i < 1024; i += 256) {
    size_t base = (size_t)(mb + (i >> 4)) * 256 + (i & 15);
    Bsh[i] = dbc[base + 128];
    Csh[i] = dbc[base + 144];
  }
  __syncthreads();

  float A[16];
  const float4* al = reinterpret_cast<const float4*>(A_log + (size_t)e * 16);
#pragma unroll
  for (int q = 0; q < 4; ++q) {
    float4 v = al[q];
    A[q * 4 + 0] = -__expf(v.x); A[q * 4 + 1] = -__expf(v.y);
    A[q * 4 + 2] = -__expf(v.z); A[q * 4 + 3] = -__expf(v.w);
  }
  float h[16];
  const float* hp = hcarry + ((size_t)bc * 4096 + e) * 16;
#pragma unroll
  for (int s = 0; s < 16; ++s) h[s] = hp[s];
  const float Dv = Dp[e];

  for (int ll = 0; ll < 64; ++ll) {
    const size_t m = (size_t)(mb + ll);
    float dl = delta[m * 4096 + e];
    float xcv = xc[m * 4096 + e];
    float dxc = dl * xcv;
    float y = 0.f;
#pragma unroll
    for (int s = 0; s < 16; ++s) {
      float dA = __expf(dl * A[s]);
      h[s] = fmaf(dA, h[s], Bsh[ll * 16 + s] * dxc);
      y = fmaf(h[s], Csh[ll * 16 + s], y);
    }
    float z = xz[m * 8192 + 4096 + e];
    y = (y + xcv * Dv) * silu_f(z);
    y_bf[m * 4096 + e] = f2bf(y);
  }
}

// ---------------------------------------------------------------------------
extern "C" void kernel_launch(void* const* d_in, const int* in_sizes, int n_in,
                              void* d_out, int out_size, void* d_ws, size_t ws_size,
                              hipStream_t stream) {
  const float* x      = (const float*)d_in[0];
  const float* W_in   = (const float*)d_in[1];
  const float* conv_w = (const float*)d_in[2];
  const float* conv_b = (const float*)d_in[3];
  const float* W_x    = (const float*)d_in[4];
  const float* W_dt   = (const float*)d_in[5];
  const float* b_dt   = (const float*)d_in[6];
  const float* A_log  = (const float*)d_in[7];
  const float* Dp     = (const float*)d_in[8];
  const float* W_out  = (const float*)d_in[9];
  float* out = (float*)d_out;
  char* ws = (char*)d_ws;

  // workspace layout (190,316,544 bytes; time-disjoint aliases marked)
  // slot0 (ws+0, 33.55 MB) timeline: Win_bf -> GEMM2 partials -> delta ->
  //                                  GEMM4 partials
  unsigned short* Win_bf    = (unsigned short*)(ws + 0);
  float*          gpart     = (float*)(ws + 0);                   // split-K partials
  float*          delta     = (float*)(ws + 0);
  unsigned short* x_bf      = (unsigned short*)(ws + 33554432);   // 8.39 MB used
  unsigned short* y_bf      = (unsigned short*)(ws + 33554432);   // alias (after GEMM1)
  unsigned short* Wout_bf   = (unsigned short*)(ws + 50331648);   // 16.78 MB
  unsigned short* Wx_bf     = (unsigned short*)(ws + 67108864);   // 2.10 MB (padded 256 rows)
  unsigned short* Wdt_bf    = (unsigned short*)(ws + 69206016);   // 1.05 MB
  float*          xz        = (float*)(ws + 70254592);            // 67.11 MB
  float*          xc        = (float*)(ws + 137363456);           // 33.55 MB
  unsigned short* xc_bf     = (unsigned short*)(ws + 170917888);  // 16.78 MB (dead after GEMM2)
  float*          hfin      = (float*)(ws + 170917888);           // alias: 8.39 MB
  float*          Pprod     = (float*)(ws + 179306496);           // alias: 8.39 MB
  float*          dbc       = (float*)(ws + 187695104);           // 2.10 MB ([2048][256])
  unsigned short* dt_bf     = (unsigned short*)(ws + 189792256);  // 0.52 MB

  // casts (bf16 operands for MFMA GEMMs)
  cast_f32_to_bf16<<<4096, 256, 0, stream>>>(x, x_bf, 1048576);
  cast_f32_to_bf16<<<16384, 256, 0, stream>>>(W_in, Win_bf, 4194304);
  cast_f32_to_bf16<<<8192, 256, 0, stream>>>(W_out, Wout_bf, 2097152);
  cast_wx_pad<<<4096, 256, 0, stream>>>(W_x, Wx_bf);
  cast_f32_to_bf16<<<512, 256, 0, stream>>>(W_dt, Wdt_bf, 131072);

  // GEMM1: xz[2048][8192] = x[2048][2048] @ W_in[8192][2048]^T  (8-phase 256^2)
  gemm_bt_8ph<<<256, 512, 0, stream>>>(x_bf, Win_bf, xz, 2048, 8192, 2048, 8);

  // conv + silu -> xc (fp32 + bf16)
  conv_silu_kernel<<<32768, 256, 0, stream>>>(xz, conv_w, conv_b, xc, xc_bf);

  // GEMM2 (split-K=8): partials[8][2048][256] = xc @ Wx_pad^T
  gemm_bt<<<dim3(2, 16, 8), 256, 0, stream>>>(xc_bf, Wx_bf, gpart, 2048, 256, 4096, 512, nullptr);
  // reduce -> dbc fp32 + dt_bf (fused cast of dt columns)
  reduce8_dbc<<<2048, 256, 0, stream>>>(gpart, dbc, dt_bf);

  // GEMM3 (+fused bias+softplus): delta[2048][4096] = sp(dt @ W_dt^T + b_dt)
  gemm_bt<<<dim3(32, 16, 1), 256, 0, stream>>>(dt_bf, Wdt_bf, delta, 2048, 4096, 128, 128, b_dt);

  // SSM scan: chunked two-pass
  scan_pass1<<<512, 256, 0, stream>>>(delta, dbc, xc, A_log, hfin, Pprod);
  scan_pass2<<<512, 256, 0, stream>>>(hfin, Pprod);
  scan_pass3<<<512, 256, 0, stream>>>(delta, dbc, xc, xz, A_log, Dp, hfin, y_bf);

  // GEMM4 (split-K=2): partials[2][2048][2048] = y @ W_out^T  (delta now dead)
  gemm_bt<<<dim3(16, 16, 2), 256, 0, stream>>>(y_bf, Wout_bf, gpart, 2048, 2048, 4096, 2048, nullptr);
  reduce2_out<<<4096, 256, 0, stream>>>(gpart, out);
}

// Round 6
// 384.732 us; speedup vs baseline: 3.5846x; 1.0135x over previous
//
#include <hip/hip_runtime.h>
#include <cstdint>

// ---------------------------------------------------------------------------
// Mamba block: xz=x@W_in^T -> split(xp,z) -> causal depthwise conv4+silu ->
// dbc=xc@W_x^T -> split(dt,B,C) -> delta=softplus(dt@W_dt^T+b_dt) ->
// diagonal SSM scan (chunked, 2-pass) -> y=(sum_s h*C + xc*D)*silu(z) ->
// out=y@W_out^T
// Shapes: B=2,L=1024 (M=2048), D_MODEL=2048, D_INNER=4096, D_STATE=16,
// DT_RANK=128, D_CONV=4.
// GEMM1: 256^2 tile, BK=64, fine 4-phase/tile schedule (T2+T3+T4+T5),
//        counted vmcnt(4) once per tile, 2 barriers per tile.
// GEMM2: m97 128^2 split-K=8 (+fused reduce->dbc,dt_bf).
// GEMM3: m97 128^2, fused bias+softplus epilogue.
// GEMM4: m97 128^2 split-K=2 (+float4 reduce).
// ---------------------------------------------------------------------------

typedef __bf16 bf16x8 __attribute__((ext_vector_type(8)));
typedef float f32x4 __attribute__((ext_vector_type(4)));

__device__ __forceinline__ unsigned short f2bf(float f) {
  uint32_t u = __float_as_uint(f);
  u += 0x7FFFu + ((u >> 16) & 1u);   // round-to-nearest-even
  return (unsigned short)(u >> 16);
}

__device__ __forceinline__ float silu_f(float v) {
  return v / (1.f + __expf(-v));
}

__device__ __forceinline__ float softplus_f(float v) {
  return (v > 20.f) ? v : log1pf(__expf(v));
}

// ---------------- cast kernels ----------------
__global__ void cast_f32_to_bf16(const float* __restrict__ src,
                                 unsigned short* __restrict__ dst, int n4) {
  int i = blockIdx.x * 256 + threadIdx.x;
  if (i >= n4) return;
  float4 v = reinterpret_cast<const float4*>(src)[i];
  ushort4 o;
  o.x = f2bf(v.x); o.y = f2bf(v.y); o.z = f2bf(v.z); o.w = f2bf(v.w);
  reinterpret_cast<ushort4*>(dst)[i] = o;
}

// W_x is [160][4096]; pad to [256][4096] with zero rows so GEMM2 needs no guards.
__global__ void cast_wx_pad(const float* __restrict__ Wx,
                            unsigned short* __restrict__ dst) {
  int i = blockIdx.x * 256 + threadIdx.x;   // over 256*4096
  int r = i >> 12;
  float v = (r < 160) ? Wx[(size_t)r * 4096 + (i & 4095)] : 0.f;
  dst[i] = f2bf(v);
}

// ---------------- m97-style bf16 MFMA GEMM (128^2, BK=32, split-K) --------
#define BM 128
#define BN 128
#define BKK 32

__device__ __forceinline__ void stage_tile(const unsigned short* __restrict__ G,
                                           int ldK, int g0, int k0,
                                           unsigned short* lds, int wave, int lane) {
#pragma unroll
  for (int c = 0; c < 2; ++c) {
    int row = c * 64 + wave * 16 + (lane >> 2);
    int col = (lane & 3) * 8;
    const unsigned short* src = G + (size_t)(g0 + row) * ldK + (k0 + col);
    unsigned short* dst = lds + c * 2048 + wave * 512;  // ushort units
    __builtin_amdgcn_global_load_lds((__attribute__((address_space(1))) void*)(src),
                                     (__attribute__((address_space(3))) void*)(dst),
                                     16, 0, 0);
  }
}

__global__ __launch_bounds__(256)
void gemm_bt(const unsigned short* __restrict__ A, const unsigned short* __restrict__ B,
             float* __restrict__ C, int M, int N, int ldK, int kchunk,
             const float* __restrict__ bias_sp) {
  __shared__ unsigned short As[BM * BKK];
  __shared__ unsigned short Bs[BN * BKK];
  const int tid = threadIdx.x;
  const int wave = tid >> 6, lane = tid & 63;
  const int wr = wave >> 1, wc = wave & 1;   // 2x2 waves, each owns 64x64 output
  const int m0 = blockIdx.y * BM, n0 = blockIdx.x * BN;
  const int lr = lane & 15, lg = lane >> 4;
  const int kb = blockIdx.z * kchunk, ke = kb + kchunk;
  C += (size_t)blockIdx.z * M * N;

  f32x4 zero = {0.f, 0.f, 0.f, 0.f};
  f32x4 acc[4][4];
#pragma unroll
  for (int i = 0; i < 4; ++i)
#pragma unroll
    for (int j = 0; j < 4; ++j) acc[i][j] = zero;

  for (int k0 = kb; k0 < ke; k0 += BKK) {
    stage_tile(A, ldK, m0, k0, As, wave, lane);
    stage_tile(B, ldK, n0, k0, Bs, wave, lane);
    __syncthreads();   // drains vmcnt (global_load_lds) + lgkm
    bf16x8 af[4], bfr[4];
#pragma unroll
    for (int i = 0; i < 4; ++i)
      af[i] = *reinterpret_cast<const bf16x8*>(&As[(wr * 64 + i * 16 + lr) * BKK + lg * 8]);
#pragma unroll
    for (int j = 0; j < 4; ++j)
      bfr[j] = *reinterpret_cast<const bf16x8*>(&Bs[(wc * 64 + j * 16 + lr) * BKK + lg * 8]);
#pragma unroll
    for (int i = 0; i < 4; ++i)
#pragma unroll
      for (int j = 0; j < 4; ++j)
        acc[i][j] = __builtin_amdgcn_mfma_f32_16x16x32_bf16(af[i], bfr[j], acc[i][j], 0, 0, 0);
    __syncthreads();
  }

  // C/D layout (m89-verified): col = lane&15, row = (lane>>4)*4 + reg
#pragma unroll
  for (int i = 0; i < 4; ++i) {
#pragma unroll
    for (int j = 0; j < 4; ++j) {
      int mrow = m0 + wr * 64 + i * 16 + lg * 4;
      int ncol = n0 + wc * 64 + j * 16 + lr;
      if (bias_sp) {
        float bv = bias_sp[ncol];
#pragma unroll
        for (int r = 0; r < 4; ++r)
          C[(size_t)(mrow + r) * N + ncol] = softplus_f(acc[i][j][r] + bv);
      } else {
#pragma unroll
        for (int r = 0; r < 4; ++r)
          C[(size_t)(mrow + r) * N + ncol] = acc[i][j][r];
      }
    }
  }
}

// split-K reducers --------------------------------------------------------
__global__ void reduce8_dbc(const float* __restrict__ p, float* __restrict__ dbc,
                            unsigned short* __restrict__ dt_bf) {
  int i = blockIdx.x * 256 + threadIdx.x;   // over 524288
  float s = 0.f;
#pragma unroll
  for (int c = 0; c < 8; ++c) s += p[(size_t)c * 524288 + i];
  dbc[i] = s;
  int col = i & 255;
  if (col < 128) dt_bf[(size_t)(i >> 8) * 128 + col] = f2bf(s);
}

__global__ void reduce2_out(const float* __restrict__ p, float* __restrict__ out) {
  int i = blockIdx.x * 256 + threadIdx.x;   // over 1048576 float4s
  const float4* p4 = reinterpret_cast<const float4*>(p);
  float4 a = p4[i], b = p4[i + 1048576];
  float4 r; r.x = a.x + b.x; r.y = a.y + b.y; r.z = a.z + b.z; r.w = a.w + b.w;
  reinterpret_cast<float4*>(out)[i] = r;
}

// ---------------- 256^2-tile fine 4-phase/tile GEMM (T2+T3+T4+T5) ----------
// 512 threads = 8 waves (2M x 4N), per-wave 128x64 output. BK=64 per tile,
// 2 LDS buffers (128 KB). Per tile t (buffer t&1), 4 phases:
//  ph0: issue Q(t+1,1); vmcnt(4); BAR; ds_read a_lo(8)+b01(4); lgkm0; MFMA16
//  ph1: issue Q(t+1,2); ds_read b23(4);  lgkm0; MFMA16
//  ph2: issue Q(t+1,3); ds_read a_hi(8); lgkm0; MFMA16; BAR (buf reads done)
//  ph3: issue Q(t+2,0); MFMA16 (regs live)
// Quantum Q = 16KB half-tile (2 x global_load_lds x 512 thr). Refill of a
// buffer is only issued after the closing barrier of the tile that last
// read it; counted vmcnt(4) = the 2 newest quanta (next tile's q0,q1).
// T2: LDS linear dest + inverse-swizzled global src col; reads XOR
// ((row&7)<<3) ushorts -> 8-way bank spread (2-way residual = free).
// Requires M%256==0, N%256==0, K%64==0, K>=128, gridDim.x%8==0.
__global__ __launch_bounds__(512, 2)
void gemm_bt_8ph(const unsigned short* __restrict__ A,
                 const unsigned short* __restrict__ B,
                 float* __restrict__ C, int M, int N, int K, int nbm) {
  __shared__ unsigned short As[2][16384];   // [buf][256 rows][64 cols]
  __shared__ unsigned short Bs[2][16384];
  const int tid = threadIdx.x;
  const int wid = tid >> 6, lane = tid & 63;
  const int wr = wid >> 2, wc = wid & 3;     // 2 x 4 waves
  const int lr = lane & 15, lg = lane >> 4;

  // XCD-bijective swizzle (gridDim.x % 8 == 0), bm-fast linearization
  const int cpx = gridDim.x >> 3;
  const int x = blockIdx.x;
  const int wg = (x & 7) * cpx + (x >> 3);
  const int bm = wg % nbm, bn = wg / nbm;
  const int m0 = bm * 256, n0 = bn * 256;

  // staging geometry: quantum = 128 rows x 64 cols (16KB), 2 rounds of
  // 512thr x 16B. round r: row = r*64 + tid/8, dest col = (tid&7)*8,
  // src col = dest col ^ ((row&7)<<3).
  const int strow = tid >> 3;
  const int stcol0 = (tid & 7) * 8;

  f32x4 acc[8][4];
  f32x4 zero = {0.f, 0.f, 0.f, 0.f};
#pragma unroll
  for (int i = 0; i < 8; ++i)
#pragma unroll
    for (int j = 0; j < 4; ++j) acc[i][j] = zero;

  const int nt = K / 64;

  // q: 0=A rows 0-127, 1=A rows 128-255, 2=B rows 0-127, 3=B rows 128-255
  auto QUANT = [&](int t, int q) {
    const int buf = t & 1;
    const unsigned short* G = (q < 2) ? A : B;
    const int g0 = ((q < 2) ? m0 : n0) + ((q & 1) ? 128 : 0);
    unsigned short* lds = ((q < 2) ? &As[buf][0] : &Bs[buf][0]) + ((q & 1) ? 8192 : 0);
    const int k0 = t * 64;
#pragma unroll
    for (int r = 0; r < 2; ++r) {
      int row = r * 64 + strow;
      int scol = stcol0 ^ ((row & 7) << 3);
      const unsigned short* src = G + (size_t)(g0 + row) * K + (k0 + scol);
      __builtin_amdgcn_global_load_lds(
          (__attribute__((address_space(1))) const void*)(src),
          (__attribute__((address_space(3))) void*)(lds + r * 4096 + tid * 8),
          16, 0, 0);
    }
  };

  auto RD_A = [&](int buf, int mf, int ks) -> bf16x8 {
    int row = wr * 128 + mf * 16 + lr;
    int col = (ks * 32 + lg * 8) ^ ((row & 7) << 3);
    return *reinterpret_cast<const bf16x8*>(&As[buf][row * 64 + col]);
  };
  auto RD_B = [&](int buf, int nf, int ks) -> bf16x8 {
    int row = wc * 64 + nf * 16 + lr;
    int col = (ks * 32 + lg * 8) ^ ((row & 7) << 3);
    return *reinterpret_cast<const bf16x8*>(&Bs[buf][row * 64 + col]);
  };

  // prologue: tile0 fully + first quantum of tile1
  QUANT(0, 0); QUANT(0, 1); QUANT(0, 2); QUANT(0, 3);
  QUANT(1, 0);

  bf16x8 a[4][2], b[4][2];
  for (int t = 0; t < nt; ++t) {
    const int buf = t & 1;
    const bool pf1 = (t + 1 < nt);
    // ---------------- ph0 ----------------
    if (pf1) {
      QUANT(t + 1, 1);
      asm volatile("s_waitcnt vmcnt(4)" ::: "memory");
    } else {
      asm volatile("s_waitcnt vmcnt(0)" ::: "memory");
    }
    __builtin_amdgcn_s_barrier();
#pragma unroll
    for (int mf = 0; mf < 4; ++mf)
#pragma unroll
      for (int ks = 0; ks < 2; ++ks) a[mf][ks] = RD_A(buf, mf, ks);
#pragma unroll
    for (int nf = 0; nf < 2; ++nf)
#pragma unroll
      for (int ks = 0; ks < 2; ++ks) b[nf][ks] = RD_B(buf, nf, ks);
    asm volatile("s_waitcnt lgkmcnt(0)" ::: "memory");
    __builtin_amdgcn_sched_barrier(0);
    __builtin_amdgcn_s_setprio(1);
#pragma unroll
    for (int nf = 0; nf < 2; ++nf)
#pragma unroll
      for (int mf = 0; mf < 4; ++mf)
#pragma unroll
        for (int ks = 0; ks < 2; ++ks)
          acc[mf][nf] = __builtin_amdgcn_mfma_f32_16x16x32_bf16(a[mf][ks], b[nf][ks], acc[mf][nf], 0, 0, 0);
    __builtin_amdgcn_s_setprio(0);
    // ---------------- ph1 ----------------
    if (pf1) QUANT(t + 1, 2);
#pragma unroll
    for (int nf = 2; nf < 4; ++nf)
#pragma unroll
      for (int ks = 0; ks < 2; ++ks) b[nf][ks] = RD_B(buf, nf, ks);
    asm volatile("s_waitcnt lgkmcnt(0)" ::: "memory");
    __builtin_amdgcn_sched_barrier(0);
    __builtin_amdgcn_s_setprio(1);
#pragma unroll
    for (int nf = 2; nf < 4; ++nf)
#pragma unroll
      for (int mf = 0; mf < 4; ++mf)
#pragma unroll
        for (int ks = 0; ks < 2; ++ks)
          acc[mf][nf] = __builtin_amdgcn_mfma_f32_16x16x32_bf16(a[mf][ks], b[nf][ks], acc[mf][nf], 0, 0, 0);
    __builtin_amdgcn_s_setprio(0);
    // ---------------- ph2 ----------------
    if (pf1) QUANT(t + 1, 3);
#pragma unroll
    for (int mf = 0; mf < 4; ++mf)
#pragma unroll
      for (int ks = 0; ks < 2; ++ks) a[mf][ks] = RD_A(buf, mf + 4, ks);
    asm volatile("s_waitcnt lgkmcnt(0)" ::: "memory");
    __builtin_amdgcn_sched_barrier(0);
    __builtin_amdgcn_s_setprio(1);
#pragma unroll
    for (int nf = 0; nf < 2; ++nf)
#pragma unroll
      for (int mf = 0; mf < 4; ++mf)
#pragma unroll
        for (int ks = 0; ks < 2; ++ks)
          acc[mf + 4][nf] = __builtin_amdgcn_mfma_f32_16x16x32_bf16(a[mf][ks], b[nf][ks], acc[mf + 4][nf], 0, 0, 0);
    __builtin_amdgcn_s_setprio(0);
    __builtin_amdgcn_s_barrier();          // all reads of buf complete
    // ---------------- ph3 ----------------
    if (t + 2 < nt) QUANT(t + 2, 0);       // refill buf (dead) for tile t+2
    __builtin_amdgcn_s_setprio(1);
#pragma unroll
    for (int nf = 2; nf < 4; ++nf)
#pragma unroll
      for (int mf = 0; mf < 4; ++mf)
#pragma unroll
        for (int ks = 0; ks < 2; ++ks)
          acc[mf + 4][nf] = __builtin_amdgcn_mfma_f32_16x16x32_bf16(a[mf][ks], b[nf][ks], acc[mf + 4][nf], 0, 0, 0);
    __builtin_amdgcn_s_setprio(0);
  }

  // Epilogue: C/D layout col=lane&15, row=(lane>>4)*4+reg (m89-verified)
#pragma unroll
  for (int mf = 0; mf < 8; ++mf) {
#pragma unroll
    for (int nf = 0; nf < 4; ++nf) {
      int mrow = m0 + wr * 128 + mf * 16 + lg * 4;
      int ncol = n0 + wc * 64 + nf * 16 + lr;
#pragma unroll
      for (int r = 0; r < 4; ++r)
        C[(size_t)(mrow + r) * N + ncol] = acc[mf][nf][r];
    }
  }
}

// ---------------- conv(4, causal, depthwise) + silu ----------------
__global__ void conv_silu_kernel(const float* __restrict__ xz,
                                 const float* __restrict__ conv_w,
                                 const float* __restrict__ conv_b,
                                 float* __restrict__ xc,
                                 unsigned short* __restrict__ xc_bf) {
  int idx = blockIdx.x * 256 + threadIdx.x;  // over 2048*4096
  int e = idx & 4095;
  int m = idx >> 12;
  int l = m & 1023;                          // within-batch position
  float acc = conv_b[e];
#pragma unroll
  for (int k = 0; k < 4; ++k) {
    int ls = l - 3 + k;
    if (ls >= 0) acc = fmaf(xz[(size_t)(m - 3 + k) * 8192 + e], conv_w[e * 4 + k], acc);
  }
  float s = silu_f(acc);
  xc[idx] = s;
  xc_bf[idx] = f2bf(s);
}

// ---------------- SSM scan: chunked 2-pass ----------------
__global__ __launch_bounds__(256)
void scan_pass1(const float* __restrict__ delta, const float* __restrict__ dbc,
                const float* __restrict__ xc, const float* __restrict__ A_log,
                float* __restrict__ hfin, float* __restrict__ Pprod) {
  __shared__ float Bsh[1024];           // [64][16]
  const int tid = threadIdx.x;
  const int bc = blockIdx.x >> 4;       // b*16 + c
  const int eg = blockIdx.x & 15;
  const int b = bc >> 4, c = bc & 15;
  const int e = eg * 256 + tid;
  const int mb = b * 1024 + c * 64;
  for (int i = tid; i < 1024; i += 256)
    Bsh[i] = dbc[(size_t)(mb + (i >> 4)) * 256 + 128 + (i & 15)];
  __syncthreads();

  float A[16];
  const float4* al = reinterpret_cast<const float4*>(A_log + (size_t)e * 16);
#pragma unroll
  for (int q = 0; q < 4; ++q) {
    float4 v = al[q];
    A[q * 4 + 0] = -__expf(v.x); A[q * 4 + 1] = -__expf(v.y);
    A[q * 4 + 2] = -__expf(v.z); A[q * 4 + 3] = -__expf(v.w);
  }
  float h[16], P[16];
#pragma unroll
  for (int s = 0; s < 16; ++s) { h[s] = 0.f; P[s] = 1.f; }

  for (int ll = 0; ll < 64; ++ll) {
    const size_t m = (size_t)(mb + ll);
    float dl = delta[m * 4096 + e];
    float dxc = dl * xc[m * 4096 + e];
#pragma unroll
    for (int s = 0; s < 16; ++s) {
      float dA = __expf(dl * A[s]);
      P[s] *= dA;
      h[s] = fmaf(dA, h[s], Bsh[ll * 16 + s] * dxc);
    }
  }
  float* hp = hfin + ((size_t)bc * 4096 + e) * 16;
  float* pp = Pprod + ((size_t)bc * 4096 + e) * 16;
#pragma unroll
  for (int s = 0; s < 16; ++s) { hp[s] = h[s]; pp[s] = P[s]; }
}

__global__ void scan_pass2(float* __restrict__ hfin, const float* __restrict__ Pprod) {
  int idx = blockIdx.x * 256 + threadIdx.x;   // 2*4096*16 = 131072
  int b = idx >> 16;
  int es = idx & 65535;                       // e*16 + s
  float H = 0.f;
  for (int c = 0; c < 16; ++c) {
    size_t o = ((size_t)(b * 16 + c) << 16) + es;
    float hf = hfin[o];
    float Pp = Pprod[o];
    hfin[o] = H;                              // carry-in for chunk c
    H = fmaf(Pp, H, hf);
  }
}

__global__ __launch_bounds__(256)
void scan_pass3(const float* __restrict__ delta, const float* __restrict__ dbc,
                const float* __restrict__ xc, const float* __restrict__ xz,
                const float* __restrict__ A_log, const float* __restrict__ Dp,
                const float* __restrict__ hcarry, unsigned short* __restrict__ y_bf) {
  __shared__ float Bsh[1024];           // [64][16]
  __shared__ float Csh[1024];
  const int tid = threadIdx.x;
  const int bc = blockIdx.x >> 4;
  const int eg = blockIdx.x & 15;
  const int b = bc >> 4, c = bc & 15;
  const int e = eg * 256 + tid;
  const int mb = b * 1024 + c * 64;
  for (int i = tid; i < 1024; i += 256) {
    size_t base = (size_t)(mb + (i >> 4)) * 256 + (i & 15);
    Bsh[i] = dbc[base + 128];
    Csh[i] = dbc[base + 144];
  }
  __syncthreads();

  float A[16];
  const float4* al = reinterpret_cast<const float4*>(A_log + (size_t)e * 16);
#pragma unroll
  for (int q = 0; q < 4; ++q) {
    float4 v = al[q];
    A[q * 4 + 0] = -__expf(v.x); A[q * 4 + 1] = -__expf(v.y);
    A[q * 4 + 2] = -__expf(v.z); A[q * 4 + 3] = -__expf(v.w);
  }
  float h[16];
  const float* hp = hcarry + ((size_t)bc * 4096 + e) * 16;
#pragma unroll
  for (int s = 0; s < 16; ++s) h[s] = hp[s];
  const float Dv = Dp[e];

  for (int ll = 0; ll < 64; ++ll) {
    const size_t m = (size_t)(mb + ll);
    float dl = delta[m * 4096 + e];
    float xcv = xc[m * 4096 + e];
    float dxc = dl * xcv;
    float y = 0.f;
#pragma unroll
    for (int s = 0; s < 16; ++s) {
      float dA = __expf(dl * A[s]);
      h[s] = fmaf(dA, h[s], Bsh[ll * 16 + s] * dxc);
      y = fmaf(h[s], Csh[ll * 16 + s], y);
    }
    float z = xz[m * 8192 + 4096 + e];
    y = (y + xcv * Dv) * silu_f(z);
    y_bf[m * 4096 + e] = f2bf(y);
  }
}

// ---------------------------------------------------------------------------
extern "C" void kernel_launch(void* const* d_in, const int* in_sizes, int n_in,
                              void* d_out, int out_size, void* d_ws, size_t ws_size,
                              hipStream_t stream) {
  const float* x      = (const float*)d_in[0];
  const float* W_in   = (const float*)d_in[1];
  const float* conv_w = (const float*)d_in[2];
  const float* conv_b = (const float*)d_in[3];
  const float* W_x    = (const float*)d_in[4];
  const float* W_dt   = (const float*)d_in[5];
  const float* b_dt   = (const float*)d_in[6];
  const float* A_log  = (const float*)d_in[7];
  const float* Dp     = (const float*)d_in[8];
  const float* W_out  = (const float*)d_in[9];
  float* out = (float*)d_out;
  char* ws = (char*)d_ws;

  // workspace layout (190,316,544 bytes; time-disjoint aliases marked)
  // slot0 (ws+0, 33.55 MB) timeline: Win_bf -> GEMM2 partials -> delta ->
  //                                  GEMM4 partials
  unsigned short* Win_bf    = (unsigned short*)(ws + 0);
  float*          gpart     = (float*)(ws + 0);                   // split-K partials
  float*          delta     = (float*)(ws + 0);
  unsigned short* x_bf      = (unsigned short*)(ws + 33554432);   // 8.39 MB used
  unsigned short* y_bf      = (unsigned short*)(ws + 33554432);   // alias (after GEMM1)
  unsigned short* Wout_bf   = (unsigned short*)(ws + 50331648);   // 16.78 MB
  unsigned short* Wx_bf     = (unsigned short*)(ws + 67108864);   // 2.10 MB (padded 256 rows)
  unsigned short* Wdt_bf    = (unsigned short*)(ws + 69206016);   // 1.05 MB
  float*          xz        = (float*)(ws + 70254592);            // 67.11 MB
  float*          xc        = (float*)(ws + 137363456);           // 33.55 MB
  unsigned short* xc_bf     = (unsigned short*)(ws + 170917888);  // 16.78 MB (dead after GEMM2)
  float*          hfin      = (float*)(ws + 170917888);           // alias: 8.39 MB
  float*          Pprod     = (float*)(ws + 179306496);           // alias: 8.39 MB
  float*          dbc       = (float*)(ws + 187695104);           // 2.10 MB ([2048][256])
  unsigned short* dt_bf     = (unsigned short*)(ws + 189792256);  // 0.52 MB

  // casts (bf16 operands for MFMA GEMMs)
  cast_f32_to_bf16<<<4096, 256, 0, stream>>>(x, x_bf, 1048576);
  cast_f32_to_bf16<<<16384, 256, 0, stream>>>(W_in, Win_bf, 4194304);
  cast_f32_to_bf16<<<8192, 256, 0, stream>>>(W_out, Wout_bf, 2097152);
  cast_wx_pad<<<4096, 256, 0, stream>>>(W_x, Wx_bf);
  cast_f32_to_bf16<<<512, 256, 0, stream>>>(W_dt, Wdt_bf, 131072);

  // GEMM1: xz[2048][8192] = x[2048][2048] @ W_in[8192][2048]^T  (fine 4-phase)
  gemm_bt_8ph<<<256, 512, 0, stream>>>(x_bf, Win_bf, xz, 2048, 8192, 2048, 8);

  // conv + silu -> xc (fp32 + bf16)
  conv_silu_kernel<<<32768, 256, 0, stream>>>(xz, conv_w, conv_b, xc, xc_bf);

  // GEMM2 (split-K=8): partials[8][2048][256] = xc @ Wx_pad^T
  gemm_bt<<<dim3(2, 16, 8), 256, 0, stream>>>(xc_bf, Wx_bf, gpart, 2048, 256, 4096, 512, nullptr);
  // reduce -> dbc fp32 + dt_bf (fused cast of dt columns)
  reduce8_dbc<<<2048, 256, 0, stream>>>(gpart, dbc, dt_bf);

  // GEMM3 (+fused bias+softplus): delta[2048][4096] = sp(dt @ W_dt^T + b_dt)
  gemm_bt<<<dim3(32, 16, 1), 256, 0, stream>>>(dt_bf, Wdt_bf, delta, 2048, 4096, 128, 128, b_dt);

  // SSM scan: chunked two-pass
  scan_pass1<<<512, 256, 0, stream>>>(delta, dbc, xc, A_log, hfin, Pprod);
  scan_pass2<<<512, 256, 0, stream>>>(hfin, Pprod);
  scan_pass3<<<512, 256, 0, stream>>>(delta, dbc, xc, xz, A_log, Dp, hfin, y_bf);

  // GEMM4 (split-K=2): partials[2][2048][2048] = y @ W_out^T  (delta now dead)
  gemm_bt<<<dim3(16, 16, 2), 256, 0, stream>>>(y_bf, Wout_bf, gpart, 2048, 2048, 4096, 2048, nullptr);
  reduce2_out<<<4096, 256, 0, stream>>>(gpart, out);
}

// Round 7
// 366.630 us; speedup vs baseline: 3.7615x; 1.0494x over previous
//
#include <hip/hip_runtime.h>
#include <cstdint>

// ---------------------------------------------------------------------------
// Mamba block. GEMM1: 256^2 tile, BK=64 split into 2 K-halves, m201-faithful
// phase order {reads -> stage -> vmcnt -> bar -> lgkm0 -> MFMA -> bar},
// counted vmcnt(6/4), T2 swizzle, setprio. GEMM2: m97 split-K=8. GEMM3: m97
// +bias/softplus. GEMM4: m97 split-K=2. Scan: chunked 2-pass.
// ---------------------------------------------------------------------------

typedef __bf16 bf16x8 __attribute__((ext_vector_type(8)));
typedef float f32x4 __attribute__((ext_vector_type(4)));

__device__ __forceinline__ unsigned short f2bf(float f) {
  uint32_t u = __float_as_uint(f);
  u += 0x7FFFu + ((u >> 16) & 1u);   // round-to-nearest-even
  return (unsigned short)(u >> 16);
}

__device__ __forceinline__ float silu_f(float v) {
  return v / (1.f + __expf(-v));
}

__device__ __forceinline__ float softplus_f(float v) {
  return (v > 20.f) ? v : log1pf(__expf(v));
}

// ---------------- cast kernels ----------------
__global__ void cast_f32_to_bf16(const float* __restrict__ src,
                                 unsigned short* __restrict__ dst, int n4) {
  int i = blockIdx.x * 256 + threadIdx.x;
  if (i >= n4) return;
  float4 v = reinterpret_cast<const float4*>(src)[i];
  ushort4 o;
  o.x = f2bf(v.x); o.y = f2bf(v.y); o.z = f2bf(v.z); o.w = f2bf(v.w);
  reinterpret_cast<ushort4*>(dst)[i] = o;
}

__global__ void cast_wx_pad(const float* __restrict__ Wx,
                            unsigned short* __restrict__ dst) {
  int i = blockIdx.x * 256 + threadIdx.x;   // over 256*4096
  int r = i >> 12;
  float v = (r < 160) ? Wx[(size_t)r * 4096 + (i & 4095)] : 0.f;
  dst[i] = f2bf(v);
}

// ---------------- m97-style bf16 MFMA GEMM (128^2, BK=32, split-K) --------
#define BM 128
#define BN 128
#define BKK 32

__device__ __forceinline__ void stage_tile(const unsigned short* __restrict__ G,
                                           int ldK, int g0, int k0,
                                           unsigned short* lds, int wave, int lane) {
#pragma unroll
  for (int c = 0; c < 2; ++c) {
    int row = c * 64 + wave * 16 + (lane >> 2);
    int col = (lane & 3) * 8;
    const unsigned short* src = G + (size_t)(g0 + row) * ldK + (k0 + col);
    unsigned short* dst = lds + c * 2048 + wave * 512;  // ushort units
    __builtin_amdgcn_global_load_lds((__attribute__((address_space(1))) void*)(src),
                                     (__attribute__((address_space(3))) void*)(dst),
                                     16, 0, 0);
  }
}

__global__ __launch_bounds__(256)
void gemm_bt(const unsigned short* __restrict__ A, const unsigned short* __restrict__ B,
             float* __restrict__ C, int M, int N, int ldK, int kchunk,
             const float* __restrict__ bias_sp) {
  __shared__ unsigned short As[BM * BKK];
  __shared__ unsigned short Bs[BN * BKK];
  const int tid = threadIdx.x;
  const int wave = tid >> 6, lane = tid & 63;
  const int wr = wave >> 1, wc = wave & 1;
  const int m0 = blockIdx.y * BM, n0 = blockIdx.x * BN;
  const int lr = lane & 15, lg = lane >> 4;
  const int kb = blockIdx.z * kchunk, ke = kb + kchunk;
  C += (size_t)blockIdx.z * M * N;

  f32x4 zero = {0.f, 0.f, 0.f, 0.f};
  f32x4 acc[4][4];
#pragma unroll
  for (int i = 0; i < 4; ++i)
#pragma unroll
    for (int j = 0; j < 4; ++j) acc[i][j] = zero;

  for (int k0 = kb; k0 < ke; k0 += BKK) {
    stage_tile(A, ldK, m0, k0, As, wave, lane);
    stage_tile(B, ldK, n0, k0, Bs, wave, lane);
    __syncthreads();
    bf16x8 af[4], bfr[4];
#pragma unroll
    for (int i = 0; i < 4; ++i)
      af[i] = *reinterpret_cast<const bf16x8*>(&As[(wr * 64 + i * 16 + lr) * BKK + lg * 8]);
#pragma unroll
    for (int j = 0; j < 4; ++j)
      bfr[j] = *reinterpret_cast<const bf16x8*>(&Bs[(wc * 64 + j * 16 + lr) * BKK + lg * 8]);
#pragma unroll
    for (int i = 0; i < 4; ++i)
#pragma unroll
      for (int j = 0; j < 4; ++j)
        acc[i][j] = __builtin_amdgcn_mfma_f32_16x16x32_bf16(af[i], bfr[j], acc[i][j], 0, 0, 0);
    __syncthreads();
  }

#pragma unroll
  for (int i = 0; i < 4; ++i) {
#pragma unroll
    for (int j = 0; j < 4; ++j) {
      int mrow = m0 + wr * 64 + i * 16 + lg * 4;
      int ncol = n0 + wc * 64 + j * 16 + lr;
      if (bias_sp) {
        float bv = bias_sp[ncol];
#pragma unroll
        for (int r = 0; r < 4; ++r)
          C[(size_t)(mrow + r) * N + ncol] = softplus_f(acc[i][j][r] + bv);
      } else {
#pragma unroll
        for (int r = 0; r < 4; ++r)
          C[(size_t)(mrow + r) * N + ncol] = acc[i][j][r];
      }
    }
  }
}

// split-K reducers --------------------------------------------------------
__global__ void reduce8_dbc(const float* __restrict__ p, float* __restrict__ dbc,
                            unsigned short* __restrict__ dt_bf) {
  int i = blockIdx.x * 256 + threadIdx.x;   // over 524288
  float s = 0.f;
#pragma unroll
  for (int c = 0; c < 8; ++c) s += p[(size_t)c * 524288 + i];
  dbc[i] = s;
  int col = i & 255;
  if (col < 128) dt_bf[(size_t)(i >> 8) * 128 + col] = f2bf(s);
}

__global__ void reduce2_out(const float* __restrict__ p, float* __restrict__ out) {
  int i = blockIdx.x * 256 + threadIdx.x;   // over 1048576 float4s
  const float4* p4 = reinterpret_cast<const float4*>(p);
  float4 a = p4[i], b = p4[i + 1048576];
  float4 r; r.x = a.x + b.x; r.y = a.y + b.y; r.z = a.z + b.z; r.w = a.w + b.w;
  reinterpret_cast<float4*>(out)[i] = r;
}

// ---------------- 256^2-tile m201-faithful pipelined GEMM ------------------
// 512 threads = 8 waves (2M x 4N), per-wave 128x64 output. BK=64 as 2
// K-halves of 32 cols. LDS [buf][ks][256][32] (128 KB). Staging quantum =
// one (matrix, ks) half = 16 KB = 2 x global_load_lds/thread. Per tile t,
// 4 phases; phase shape (m201): reads(A) -> stage(B) -> vmcnt(C) -> bar(D)
// -> lgkm0+schedbar(E) -> setprio/16 MFMA(F) -> bar(G).
//   ph0: reads a[0..7]k0,b01k0 (10); stage A_k0(t+1); vmcnt(6)
//   ph1: reads b23k0 (2);           stage B_k0(t+1); vmcnt(4)
//   ph2: reads a[0..7]k1,b01k1(10); stage A_k1(t+1); (no wait)
//   ph3: reads b23k1 (2);           stage B_k1(t+1); vmcnt(4)
// Wait derivation: allowed-outstanding = halves issued AFTER the half the
// NEXT phase reads (2 loads each); never 0 mid-loop. Reads of phase p are
// covered by phase p-1's {vmcnt;bar}. Buffer overwrite safe: last readers
// of buf^1 finished (lgkm0) before the barriers separating tiles.
// T2: linear LDS dest + inverse-swizzled global src col; read col XOR
// ((row>>1)&3)<<3 -> 2-way residual (free). Requires M,N %256==0, K%64==0.
__global__ __launch_bounds__(512, 2)
void gemm_bt_8ph(const unsigned short* __restrict__ A,
                 const unsigned short* __restrict__ B,
                 float* __restrict__ C, int M, int N, int K, int nbm) {
  __shared__ unsigned short As[2][16384];   // [buf][ks*8192 + row*32 + col]
  __shared__ unsigned short Bs[2][16384];
  const int tid = threadIdx.x;
  const int wid = tid >> 6, lane = tid & 63;
  const int wr = wid >> 2, wc = wid & 3;     // 2 x 4 waves
  const int lr = lane & 15, lg = lane >> 4;

  // XCD-bijective swizzle (gridDim.x % 8 == 0)
  const int cpx = gridDim.x >> 3;
  const int x = blockIdx.x;
  const int wg = (x & 7) * cpx + (x >> 3);
  const int bm = wg % nbm, bn = wg / nbm;
  const int m0 = bm * 256, n0 = bn * 256;

  f32x4 acc[8][4];
  f32x4 zero = {0.f, 0.f, 0.f, 0.f};
#pragma unroll
  for (int i = 0; i < 8; ++i)
#pragma unroll
    for (int j = 0; j < 4; ++j) acc[i][j] = zero;

  const int nt = K / 64;

  // q: 0 = A ks0, 1 = B ks0, 2 = A ks1, 3 = B ks1. Half = 256 rows x 32 cols.
  // round r: row = r*128 + tid/4, dest col (tid&3)*8 (linear: base+tid*16B),
  // src col inverse-swizzled.
  auto QUANT = [&](int t, int q) {
    const int buf = t & 1;
    const int ks = q >> 1;
    const unsigned short* G = (q & 1) ? B : A;
    const int g0 = (q & 1) ? n0 : m0;
    unsigned short* lds = ((q & 1) ? &Bs[buf][0] : &As[buf][0]) + ks * 8192;
    const int k0 = t * 64 + ks * 32;
#pragma unroll
    for (int r = 0; r < 2; ++r) {
      int row = r * 128 + (tid >> 2);
      int scol = ((tid & 3) * 8) ^ (((row >> 1) & 3) << 3);
      const unsigned short* src = G + (size_t)(g0 + row) * K + (k0 + scol);
      __builtin_amdgcn_global_load_lds(
          (__attribute__((address_space(1))) const void*)(src),
          (__attribute__((address_space(3))) void*)(lds + r * 4096 + tid * 8),
          16, 0, 0);
    }
  };

  auto RD_A = [&](int buf, int ks, int mf) -> bf16x8 {
    int row = wr * 128 + mf * 16 + lr;
    int col = (lg * 8) ^ (((row >> 1) & 3) << 3);
    return *reinterpret_cast<const bf16x8*>(&As[buf][ks * 8192 + row * 32 + col]);
  };
  auto RD_B = [&](int buf, int ks, int nf) -> bf16x8 {
    int row = wc * 64 + nf * 16 + lr;
    int col = (lg * 8) ^ (((row >> 1) & 3) << 3);
    return *reinterpret_cast<const bf16x8*>(&Bs[buf][ks * 8192 + row * 32 + col]);
  };

  // prologue: all 4 halves of tile 0; ensure q0,q1 landed (q2,q3 may fly)
  QUANT(0, 0); QUANT(0, 1); QUANT(0, 2); QUANT(0, 3);
  asm volatile("s_waitcnt vmcnt(4)" ::: "memory");
  __builtin_amdgcn_s_barrier();

  bf16x8 a[8], b[4];
  for (int t = 0; t < nt; ++t) {
    const int buf = t & 1;
    const bool pf = (t + 1 < nt);
    // ---------------- ph0 (ks0, nf 0-1) ----------------
#pragma unroll
    for (int mf = 0; mf < 8; ++mf) a[mf] = RD_A(buf, 0, mf);
    b[0] = RD_B(buf, 0, 0); b[1] = RD_B(buf, 0, 1);
    if (pf) {
      QUANT(t + 1, 0);
      asm volatile("s_waitcnt vmcnt(6)" ::: "memory");
    } else {
      asm volatile("s_waitcnt vmcnt(4)" ::: "memory");
    }
    __builtin_amdgcn_s_barrier();
    asm volatile("s_waitcnt lgkmcnt(0)" ::: "memory");
    __builtin_amdgcn_sched_barrier(0);
    __builtin_amdgcn_s_setprio(1);
#pragma unroll
    for (int nf = 0; nf < 2; ++nf)
#pragma unroll
      for (int mf = 0; mf < 8; ++mf)
        acc[mf][nf] = __builtin_amdgcn_mfma_f32_16x16x32_bf16(a[mf], b[nf], acc[mf][nf], 0, 0, 0);
    __builtin_amdgcn_s_setprio(0);
    __builtin_amdgcn_s_barrier();
    // ---------------- ph1 (ks0, nf 2-3) ----------------
    b[2] = RD_B(buf, 0, 2); b[3] = RD_B(buf, 0, 3);
    if (pf) {
      QUANT(t + 1, 1);
      asm volatile("s_waitcnt vmcnt(4)" ::: "memory");
    } else {
      asm volatile("s_waitcnt vmcnt(0)" ::: "memory");
    }
    __builtin_amdgcn_s_barrier();
    asm volatile("s_waitcnt lgkmcnt(0)" ::: "memory");
    __builtin_amdgcn_sched_barrier(0);
    __builtin_amdgcn_s_setprio(1);
#pragma unroll
    for (int nf = 2; nf < 4; ++nf)
#pragma unroll
      for (int mf = 0; mf < 8; ++mf)
        acc[mf][nf] = __builtin_amdgcn_mfma_f32_16x16x32_bf16(a[mf], b[nf], acc[mf][nf], 0, 0, 0);
    __builtin_amdgcn_s_setprio(0);
    __builtin_amdgcn_s_barrier();
    // ---------------- ph2 (ks1, nf 0-1) ----------------
#pragma unroll
    for (int mf = 0; mf < 8; ++mf) a[mf] = RD_A(buf, 1, mf);
    b[0] = RD_B(buf, 1, 0); b[1] = RD_B(buf, 1, 1);
    if (pf) QUANT(t + 1, 2);
    __builtin_amdgcn_s_barrier();
    asm volatile("s_waitcnt lgkmcnt(0)" ::: "memory");
    __builtin_amdgcn_sched_barrier(0);
    __builtin_amdgcn_s_setprio(1);
#pragma unroll
    for (int nf = 0; nf < 2; ++nf)
#pragma unroll
      for (int mf = 0; mf < 8; ++mf)
        acc[mf][nf] = __builtin_amdgcn_mfma_f32_16x16x32_bf16(a[mf], b[nf], acc[mf][nf], 0, 0, 0);
    __builtin_amdgcn_s_setprio(0);
    __builtin_amdgcn_s_barrier();
    // ---------------- ph3 (ks1, nf 2-3) ----------------
    b[2] = RD_B(buf, 1, 2); b[3] = RD_B(buf, 1, 3);
    if (pf) {
      QUANT(t + 1, 3);
      asm volatile("s_waitcnt vmcnt(4)" ::: "memory");
    }
    __builtin_amdgcn_s_barrier();
    asm volatile("s_waitcnt lgkmcnt(0)" ::: "memory");
    __builtin_amdgcn_sched_barrier(0);
    __builtin_amdgcn_s_setprio(1);
#pragma unroll
    for (int nf = 2; nf < 4; ++nf)
#pragma unroll
      for (int mf = 0; mf < 8; ++mf)
        acc[mf][nf] = __builtin_amdgcn_mfma_f32_16x16x32_bf16(a[mf], b[nf], acc[mf][nf], 0, 0, 0);
    __builtin_amdgcn_s_setprio(0);
    __builtin_amdgcn_s_barrier();
  }

  // Epilogue: C/D layout col=lane&15, row=(lane>>4)*4+reg (m89-verified)
#pragma unroll
  for (int mf = 0; mf < 8; ++mf) {
#pragma unroll
    for (int nf = 0; nf < 4; ++nf) {
      int mrow = m0 + wr * 128 + mf * 16 + lg * 4;
      int ncol = n0 + wc * 64 + nf * 16 + lr;
#pragma unroll
      for (int r = 0; r < 4; ++r)
        C[(size_t)(mrow + r) * N + ncol] = acc[mf][nf][r];
    }
  }
}

// ---------------- conv(4, causal, depthwise) + silu, x4 vectorized --------
__global__ void conv_silu_kernel(const float* __restrict__ xz,
                                 const float* __restrict__ conv_w,
                                 const float* __restrict__ conv_b,
                                 float* __restrict__ xc,
                                 unsigned short* __restrict__ xc_bf) {
  int i4 = blockIdx.x * 256 + threadIdx.x;   // over 2048*1024 float4 groups
  int e4 = i4 & 1023;                        // e/4 within row
  int m = i4 >> 10;
  int l = m & 1023;
  float4 cw0 = reinterpret_cast<const float4*>(conv_w)[e4 * 4 + 0];
  float4 cw1 = reinterpret_cast<const float4*>(conv_w)[e4 * 4 + 1];
  float4 cw2 = reinterpret_cast<const float4*>(conv_w)[e4 * 4 + 2];
  float4 cw3 = reinterpret_cast<const float4*>(conv_w)[e4 * 4 + 3];
  float4 acc = reinterpret_cast<const float4*>(conv_b)[e4];
#pragma unroll
  for (int k = 0; k < 4; ++k) {
    if (l - 3 + k >= 0) {
      float4 xv = reinterpret_cast<const float4*>(xz)[(size_t)(m - 3 + k) * 2048 + e4];
      acc.x = fmaf(xv.x, ((const float*)&cw0)[k], acc.x);
      acc.y = fmaf(xv.y, ((const float*)&cw1)[k], acc.y);
      acc.z = fmaf(xv.z, ((const float*)&cw2)[k], acc.z);
      acc.w = fmaf(xv.w, ((const float*)&cw3)[k], acc.w);
    }
  }
  float4 s;
  s.x = silu_f(acc.x); s.y = silu_f(acc.y);
  s.z = silu_f(acc.z); s.w = silu_f(acc.w);
  reinterpret_cast<float4*>(xc)[i4] = s;
  ushort4 o;
  o.x = f2bf(s.x); o.y = f2bf(s.y); o.z = f2bf(s.z); o.w = f2bf(s.w);
  reinterpret_cast<ushort4*>(xc_bf)[i4] = o;
}

// ---------------- SSM scan: chunked 2-pass ----------------
__global__ __launch_bounds__(256)
void scan_pass1(const float* __restrict__ delta, const float* __restrict__ dbc,
                const float* __restrict__ xc, const float* __restrict__ A_log,
                float* __restrict__ hfin, float* __restrict__ Pprod) {
  __shared__ float Bsh[1024];           // [64][16]
  const int tid = threadIdx.x;
  const int bc = blockIdx.x >> 4;       // b*16 + c
  const int eg = blockIdx.x & 15;
  const int b = bc >> 4, c = bc & 15;
  const int e = eg * 256 + tid;
  const int mb = b * 1024 + c * 64;
  for (int i = tid; i < 1024; i += 256)
    Bsh[i] = dbc[(size_t)(mb + (i >> 4)) * 256 + 128 + (i & 15)];
  __syncthreads();

  float A[16];
  const float4* al = reinterpret_cast<const float4*>(A_log + (size_t)e * 16);
#pragma unroll
  for (int q = 0; q < 4; ++q) {
    float4 v = al[q];
    A[q * 4 + 0] = -__expf(v.x); A[q * 4 + 1] = -__expf(v.y);
    A[q * 4 + 2] = -__expf(v.z); A[q * 4 + 3] = -__expf(v.w);
  }
  float h[16], P[16];
#pragma unroll
  for (int s = 0; s < 16; ++s) { h[s] = 0.f; P[s] = 1.f; }

  for (int ll = 0; ll < 64; ++ll) {
    const size_t m = (size_t)(mb + ll);
    float dl = delta[m * 4096 + e];
    float dxc = dl * xc[m * 4096 + e];
#pragma unroll
    for (int s = 0; s < 16; ++s) {
      float dA = __expf(dl * A[s]);
      P[s] *= dA;
      h[s] = fmaf(dA, h[s], Bsh[ll * 16 + s] * dxc);
    }
  }
  float* hp = hfin + ((size_t)bc * 4096 + e) * 16;
  float* pp = Pprod + ((size_t)bc * 4096 + e) * 16;
#pragma unroll
  for (int s = 0; s < 16; ++s) { hp[s] = h[s]; pp[s] = P[s]; }
}

__global__ void scan_pass2(float* __restrict__ hfin, const float* __restrict__ Pprod) {
  int idx = blockIdx.x * 256 + threadIdx.x;   // 2*4096*16 = 131072
  int b = idx >> 16;
  int es = idx & 65535;                       // e*16 + s
  float H = 0.f;
  for (int c = 0; c < 16; ++c) {
    size_t o = ((size_t)(b * 16 + c) << 16) + es;
    float hf = hfin[o];
    float Pp = Pprod[o];
    hfin[o] = H;                              // carry-in for chunk c
    H = fmaf(Pp, H, hf);
  }
}

__global__ __launch_bounds__(256)
void scan_pass3(const float* __restrict__ delta, const float* __restrict__ dbc,
                const float* __restrict__ xc, const float* __restrict__ xz,
                const float* __restrict__ A_log, const float* __restrict__ Dp,
                const float* __restrict__ hcarry, unsigned short* __restrict__ y_bf) {
  __shared__ float Bsh[1024];           // [64][16]
  __shared__ float Csh[1024];
  const int tid = threadIdx.x;
  const int bc = blockIdx.x >> 4;
  const int eg = blockIdx.x & 15;
  const int b = bc >> 4, c = bc & 15;
  const int e = eg * 256 + tid;
  const int mb = b * 1024 + c * 64;
  for (int i = tid; i < 1024; i += 256) {
    size_t base = (size_t)(mb + (i >> 4)) * 256 + (i & 15);
    Bsh[i] = dbc[base + 128];
    Csh[i] = dbc[base + 144];
  }
  __syncthreads();

  float A[16];
  const float4* al = reinterpret_cast<const float4*>(A_log + (size_t)e * 16);
#pragma unroll
  for (int q = 0; q < 4; ++q) {
    float4 v = al[q];
    A[q * 4 + 0] = -__expf(v.x); A[q * 4 + 1] = -__expf(v.y);
    A[q * 4 + 2] = -__expf(v.z); A[q * 4 + 3] = -__expf(v.w);
  }
  float h[16];
  const float* hp = hcarry + ((size_t)bc * 4096 + e) * 16;
#pragma unroll
  for (int s = 0; s < 16; ++s) h[s] = hp[s];
  const float Dv = Dp[e];

  for (int ll = 0; ll < 64; ++ll) {
    const size_t m = (size_t)(mb + ll);
    float dl = delta[m * 4096 + e];
    float xcv = xc[m * 4096 + e];
    float dxc = dl * xcv;
    float y = 0.f;
#pragma unroll
    for (int s = 0; s < 16; ++s) {
      float dA = __expf(dl * A[s]);
      h[s] = fmaf(dA, h[s], Bsh[ll * 16 + s] * dxc);
      y = fmaf(h[s], Csh[ll * 16 + s], y);
    }
    float z = xz[m * 8192 + 4096 + e];
    y = (y + xcv * Dv) * silu_f(z);
    y_bf[m * 4096 + e] = f2bf(y);
  }
}

// ---------------------------------------------------------------------------
extern "C" void kernel_launch(void* const* d_in, const int* in_sizes, int n_in,
                              void* d_out, int out_size, void* d_ws, size_t ws_size,
                              hipStream_t stream) {
  const float* x      = (const float*)d_in[0];
  const float* W_in   = (const float*)d_in[1];
  const float* conv_w = (const float*)d_in[2];
  const float* conv_b = (const float*)d_in[3];
  const float* W_x    = (const float*)d_in[4];
  const float* W_dt   = (const float*)d_in[5];
  const float* b_dt   = (const float*)d_in[6];
  const float* A_log  = (const float*)d_in[7];
  const float* Dp     = (const float*)d_in[8];
  const float* W_out  = (const float*)d_in[9];
  float* out = (float*)d_out;
  char* ws = (char*)d_ws;

  // workspace layout (190,316,544 bytes; time-disjoint aliases marked)
  // slot0 (ws+0, 33.55 MB): Win_bf -> GEMM2 partials -> delta -> GEMM4 partials
  unsigned short* Win_bf    = (unsigned short*)(ws + 0);
  float*          gpart     = (float*)(ws + 0);
  float*          delta     = (float*)(ws + 0);
  unsigned short* x_bf      = (unsigned short*)(ws + 33554432);
  unsigned short* y_bf      = (unsigned short*)(ws + 33554432);   // alias (after GEMM1)
  unsigned short* Wout_bf   = (unsigned short*)(ws + 50331648);
  unsigned short* Wx_bf     = (unsigned short*)(ws + 67108864);
  unsigned short* Wdt_bf    = (unsigned short*)(ws + 69206016);
  float*          xz        = (float*)(ws + 70254592);
  float*          xc        = (float*)(ws + 137363456);
  unsigned short* xc_bf     = (unsigned short*)(ws + 170917888);  // dead after GEMM2
  float*          hfin      = (float*)(ws + 170917888);           // alias
  float*          Pprod     = (float*)(ws + 179306496);           // alias
  float*          dbc       = (float*)(ws + 187695104);
  unsigned short* dt_bf     = (unsigned short*)(ws + 189792256);

  // casts
  cast_f32_to_bf16<<<4096, 256, 0, stream>>>(x, x_bf, 1048576);
  cast_f32_to_bf16<<<16384, 256, 0, stream>>>(W_in, Win_bf, 4194304);
  cast_f32_to_bf16<<<8192, 256, 0, stream>>>(W_out, Wout_bf, 2097152);
  cast_wx_pad<<<4096, 256, 0, stream>>>(W_x, Wx_bf);
  cast_f32_to_bf16<<<512, 256, 0, stream>>>(W_dt, Wdt_bf, 131072);

  // GEMM1: xz[2048][8192] = x[2048][2048] @ W_in[8192][2048]^T
  gemm_bt_8ph<<<256, 512, 0, stream>>>(x_bf, Win_bf, xz, 2048, 8192, 2048, 8);

  // conv + silu -> xc (fp32 + bf16)
  conv_silu_kernel<<<8192, 256, 0, stream>>>(xz, conv_w, conv_b, xc, xc_bf);

  // GEMM2 (split-K=8): partials[8][2048][256] = xc @ Wx_pad^T
  gemm_bt<<<dim3(2, 16, 8), 256, 0, stream>>>(xc_bf, Wx_bf, gpart, 2048, 256, 4096, 512, nullptr);
  reduce8_dbc<<<2048, 256, 0, stream>>>(gpart, dbc, dt_bf);

  // GEMM3 (+fused bias+softplus): delta[2048][4096] = sp(dt @ W_dt^T + b_dt)
  gemm_bt<<<dim3(32, 16, 1), 256, 0, stream>>>(dt_bf, Wdt_bf, delta, 2048, 4096, 128, 128, b_dt);

  // SSM scan: chunked two-pass
  scan_pass1<<<512, 256, 0, stream>>>(delta, dbc, xc, A_log, hfin, Pprod);
  scan_pass2<<<512, 256, 0, stream>>>(hfin, Pprod);
  scan_pass3<<<512, 256, 0, stream>>>(delta, dbc, xc, xz, A_log, Dp, hfin, y_bf);

  // GEMM4 (split-K=2): partials[2][2048][2048] = y @ W_out^T
  gemm_bt<<<dim3(16, 16, 2), 256, 0, stream>>>(y_bf, Wout_bf, gpart, 2048, 2048, 4096, 2048, nullptr);
  reduce2_out<<<4096, 256, 0, stream>>>(gpart, out);
}

// Round 8
// 350.121 us; speedup vs baseline: 3.9389x; 1.0472x over previous
//
#include <hip/hip_runtime.h>
#include <cstdint>

// ---------------------------------------------------------------------------
// Mamba block. GEMM1/GEMM4: 256^2 tile 8-wave m201-style pipelined kernel
// (T2+T3+T4+T5), GEMM4 via split-K=4 (+reduce4). GEMM2: m97 split-K=8
// (+fused reduce->dbc,dt_bf). GEMM3: m97 +bias/softplus. Scan: chunked
// 2-pass, reads xc as bf16. Single fused cast kernel.
// ---------------------------------------------------------------------------

typedef __bf16 bf16x8 __attribute__((ext_vector_type(8)));
typedef float f32x4 __attribute__((ext_vector_type(4)));

__device__ __forceinline__ unsigned short f2bf(float f) {
  uint32_t u = __float_as_uint(f);
  u += 0x7FFFu + ((u >> 16) & 1u);   // round-to-nearest-even
  return (unsigned short)(u >> 16);
}

__device__ __forceinline__ float bf2f(unsigned short v) {
  return __uint_as_float(((uint32_t)v) << 16);
}

__device__ __forceinline__ float silu_f(float v) {
  return v / (1.f + __expf(-v));
}

__device__ __forceinline__ float softplus_f(float v) {
  return (v > 20.f) ? v : log1pf(__expf(v));
}

// ---------------- fused cast kernel (all bf16 operand prep) ----------------
// float4 regions: [0,1048576) x | [.., 5242880) W_in | [.., 7340032) W_out |
// [.., 7471104) W_dt | [.., 7733248) Wx padded to 256 rows (zeros >=160).
__global__ void cast_all(const float* __restrict__ x, const float* __restrict__ W_in,
                         const float* __restrict__ W_out, const float* __restrict__ W_dt,
                         const float* __restrict__ W_x,
                         unsigned short* __restrict__ x_bf, unsigned short* __restrict__ Win_bf,
                         unsigned short* __restrict__ Wout_bf, unsigned short* __restrict__ Wdt_bf,
                         unsigned short* __restrict__ Wx_bf) {
  int i = blockIdx.x * 256 + threadIdx.x;   // over 7,733,248 float4 groups
  const float4* s4; ushort4* d4; int j;
  if (i < 1048576)      { s4 = (const float4*)x;     d4 = (ushort4*)x_bf;    j = i; }
  else if (i < 5242880) { s4 = (const float4*)W_in;  d4 = (ushort4*)Win_bf;  j = i - 1048576; }
  else if (i < 7340032) { s4 = (const float4*)W_out; d4 = (ushort4*)Wout_bf; j = i - 5242880; }
  else if (i < 7471104) { s4 = (const float4*)W_dt;  d4 = (ushort4*)Wdt_bf;  j = i - 7340032; }
  else {
    j = i - 7471104;
    ushort4 o = {0, 0, 0, 0};
    if (j < 163840) {   // 160*4096/4
      float4 v = ((const float4*)W_x)[j];
      o.x = f2bf(v.x); o.y = f2bf(v.y); o.z = f2bf(v.z); o.w = f2bf(v.w);
    }
    ((ushort4*)Wx_bf)[j] = o;
    return;
  }
  float4 v = s4[j];
  ushort4 o; o.x = f2bf(v.x); o.y = f2bf(v.y); o.z = f2bf(v.z); o.w = f2bf(v.w);
  d4[j] = o;
}

// ---------------- m97-style bf16 MFMA GEMM (128^2, BK=32, split-K) --------
#define BM 128
#define BN 128
#define BKK 32

__device__ __forceinline__ void stage_tile(const unsigned short* __restrict__ G,
                                           int ldK, int g0, int k0,
                                           unsigned short* lds, int wave, int lane) {
#pragma unroll
  for (int c = 0; c < 2; ++c) {
    int row = c * 64 + wave * 16 + (lane >> 2);
    int col = (lane & 3) * 8;
    const unsigned short* src = G + (size_t)(g0 + row) * ldK + (k0 + col);
    unsigned short* dst = lds + c * 2048 + wave * 512;  // ushort units
    __builtin_amdgcn_global_load_lds((__attribute__((address_space(1))) void*)(src),
                                     (__attribute__((address_space(3))) void*)(dst),
                                     16, 0, 0);
  }
}

__global__ __launch_bounds__(256)
void gemm_bt(const unsigned short* __restrict__ A, const unsigned short* __restrict__ B,
             float* __restrict__ C, int M, int N, int ldK, int kchunk,
             const float* __restrict__ bias_sp) {
  __shared__ unsigned short As[BM * BKK];
  __shared__ unsigned short Bs[BN * BKK];
  const int tid = threadIdx.x;
  const int wave = tid >> 6, lane = tid & 63;
  const int wr = wave >> 1, wc = wave & 1;
  const int m0 = blockIdx.y * BM, n0 = blockIdx.x * BN;
  const int lr = lane & 15, lg = lane >> 4;
  const int kb = blockIdx.z * kchunk, ke = kb + kchunk;
  C += (size_t)blockIdx.z * M * N;

  f32x4 zero = {0.f, 0.f, 0.f, 0.f};
  f32x4 acc[4][4];
#pragma unroll
  for (int i = 0; i < 4; ++i)
#pragma unroll
    for (int j = 0; j < 4; ++j) acc[i][j] = zero;

  for (int k0 = kb; k0 < ke; k0 += BKK) {
    stage_tile(A, ldK, m0, k0, As, wave, lane);
    stage_tile(B, ldK, n0, k0, Bs, wave, lane);
    __syncthreads();
    bf16x8 af[4], bfr[4];
#pragma unroll
    for (int i = 0; i < 4; ++i)
      af[i] = *reinterpret_cast<const bf16x8*>(&As[(wr * 64 + i * 16 + lr) * BKK + lg * 8]);
#pragma unroll
    for (int j = 0; j < 4; ++j)
      bfr[j] = *reinterpret_cast<const bf16x8*>(&Bs[(wc * 64 + j * 16 + lr) * BKK + lg * 8]);
#pragma unroll
    for (int i = 0; i < 4; ++i)
#pragma unroll
      for (int j = 0; j < 4; ++j)
        acc[i][j] = __builtin_amdgcn_mfma_f32_16x16x32_bf16(af[i], bfr[j], acc[i][j], 0, 0, 0);
    __syncthreads();
  }

#pragma unroll
  for (int i = 0; i < 4; ++i) {
#pragma unroll
    for (int j = 0; j < 4; ++j) {
      int mrow = m0 + wr * 64 + i * 16 + lg * 4;
      int ncol = n0 + wc * 64 + j * 16 + lr;
      if (bias_sp) {
        float bv = bias_sp[ncol];
#pragma unroll
        for (int r = 0; r < 4; ++r)
          C[(size_t)(mrow + r) * N + ncol] = softplus_f(acc[i][j][r] + bv);
      } else {
#pragma unroll
        for (int r = 0; r < 4; ++r)
          C[(size_t)(mrow + r) * N + ncol] = acc[i][j][r];
      }
    }
  }
}

// split-K reducers --------------------------------------------------------
__global__ void reduce8_dbc(const float* __restrict__ p, float* __restrict__ dbc,
                            unsigned short* __restrict__ dt_bf) {
  int i = blockIdx.x * 256 + threadIdx.x;   // over 524288
  float s = 0.f;
#pragma unroll
  for (int c = 0; c < 8; ++c) s += p[(size_t)c * 524288 + i];
  dbc[i] = s;
  int col = i & 255;
  if (col < 128) dt_bf[(size_t)(i >> 8) * 128 + col] = f2bf(s);
}

__global__ void reduce4_out(const float* __restrict__ p, float* __restrict__ out) {
  int i = blockIdx.x * 256 + threadIdx.x;   // over 1048576 float4s
  const float4* p4 = reinterpret_cast<const float4*>(p);
  float4 a = p4[i], b = p4[i + 1048576], c = p4[i + 2097152], d = p4[i + 3145728];
  float4 r;
  r.x = (a.x + b.x) + (c.x + d.x); r.y = (a.y + b.y) + (c.y + d.y);
  r.z = (a.z + b.z) + (c.z + d.z); r.w = (a.w + b.w) + (c.w + d.w);
  reinterpret_cast<float4*>(out)[i] = r;
}

// ---------------- 256^2-tile m201-faithful pipelined GEMM (+split-K) -------
// 512 threads = 8 waves (2M x 4N), per-wave 128x64. BK=64 as 2 K-halves.
// LDS [buf][ks][256][32] (128 KB). 4 phases/tile; phase shape: reads ->
// stage 1 half -> counted vmcnt -> bar -> lgkm0+schedbar -> setprio/16 MFMA
// -> bar. vmcnt never 0 mid-loop. T2 both-sides swizzle (rule #21).
// Split-K: blockIdx.z covers K-range [z*kchunk,(z+1)*kchunk), C offset
// z*M*N. Requires M,N %256==0, kchunk%64==0, gridDim.x%8==0.
__global__ __launch_bounds__(512, 2)
void gemm_bt_8ph(const unsigned short* __restrict__ A,
                 const unsigned short* __restrict__ B,
                 float* __restrict__ C, int M, int N, int K, int nbm, int kchunk) {
  __shared__ unsigned short As[2][16384];   // [buf][ks*8192 + row*32 + col]
  __shared__ unsigned short Bs[2][16384];
  const int tid = threadIdx.x;
  const int wid = tid >> 6, lane = tid & 63;
  const int wr = wid >> 2, wc = wid & 3;     // 2 x 4 waves
  const int lr = lane & 15, lg = lane >> 4;

  // XCD-bijective swizzle (gridDim.x % 8 == 0)
  const int cpx = gridDim.x >> 3;
  const int x = blockIdx.x;
  const int wg = (x & 7) * cpx + (x >> 3);
  const int bm = wg % nbm, bn = wg / nbm;
  const int m0 = bm * 256, n0 = bn * 256;
  const int kb = blockIdx.z * kchunk;
  C += (size_t)blockIdx.z * M * N;

  f32x4 acc[8][4];
  f32x4 zero = {0.f, 0.f, 0.f, 0.f};
#pragma unroll
  for (int i = 0; i < 8; ++i)
#pragma unroll
    for (int j = 0; j < 4; ++j) acc[i][j] = zero;

  const int nt = kchunk / 64;

  // q: 0 = A ks0, 1 = B ks0, 2 = A ks1, 3 = B ks1. Half = 256 rows x 32 cols.
  auto QUANT = [&](int t, int q) {
    const int buf = t & 1;
    const int ks = q >> 1;
    const unsigned short* G = (q & 1) ? B : A;
    const int g0 = (q & 1) ? n0 : m0;
    unsigned short* lds = ((q & 1) ? &Bs[buf][0] : &As[buf][0]) + ks * 8192;
    const int k0 = kb + t * 64 + ks * 32;
#pragma unroll
    for (int r = 0; r < 2; ++r) {
      int row = r * 128 + (tid >> 2);
      int scol = ((tid & 3) * 8) ^ (((row >> 1) & 3) << 3);
      const unsigned short* src = G + (size_t)(g0 + row) * K + (k0 + scol);
      __builtin_amdgcn_global_load_lds(
          (__attribute__((address_space(1))) const void*)(src),
          (__attribute__((address_space(3))) void*)(lds + r * 4096 + tid * 8),
          16, 0, 0);
    }
  };

  auto RD_A = [&](int buf, int ks, int mf) -> bf16x8 {
    int row = wr * 128 + mf * 16 + lr;
    int col = (lg * 8) ^ (((row >> 1) & 3) << 3);
    return *reinterpret_cast<const bf16x8*>(&As[buf][ks * 8192 + row * 32 + col]);
  };
  auto RD_B = [&](int buf, int ks, int nf) -> bf16x8 {
    int row = wc * 64 + nf * 16 + lr;
    int col = (lg * 8) ^ (((row >> 1) & 3) << 3);
    return *reinterpret_cast<const bf16x8*>(&Bs[buf][ks * 8192 + row * 32 + col]);
  };

  // prologue: all 4 halves of tile 0; ensure q0,q1 landed (q2,q3 may fly)
  QUANT(0, 0); QUANT(0, 1); QUANT(0, 2); QUANT(0, 3);
  asm volatile("s_waitcnt vmcnt(4)" ::: "memory");
  __builtin_amdgcn_s_barrier();

  bf16x8 a[8], b[4];
  for (int t = 0; t < nt; ++t) {
    const int buf = t & 1;
    const bool pf = (t + 1 < nt);
    // ---------------- ph0 (ks0, nf 0-1) ----------------
#pragma unroll
    for (int mf = 0; mf < 8; ++mf) a[mf] = RD_A(buf, 0, mf);
    b[0] = RD_B(buf, 0, 0); b[1] = RD_B(buf, 0, 1);
    if (pf) {
      QUANT(t + 1, 0);
      asm volatile("s_waitcnt vmcnt(6)" ::: "memory");
    } else {
      asm volatile("s_waitcnt vmcnt(4)" ::: "memory");
    }
    __builtin_amdgcn_s_barrier();
    asm volatile("s_waitcnt lgkmcnt(0)" ::: "memory");
    __builtin_amdgcn_sched_barrier(0);
    __builtin_amdgcn_s_setprio(1);
#pragma unroll
    for (int nf = 0; nf < 2; ++nf)
#pragma unroll
      for (int mf = 0; mf < 8; ++mf)
        acc[mf][nf] = __builtin_amdgcn_mfma_f32_16x16x32_bf16(a[mf], b[nf], acc[mf][nf], 0, 0, 0);
    __builtin_amdgcn_s_setprio(0);
    __builtin_amdgcn_s_barrier();
    // ---------------- ph1 (ks0, nf 2-3) ----------------
    b[2] = RD_B(buf, 0, 2); b[3] = RD_B(buf, 0, 3);
    if (pf) {
      QUANT(t + 1, 1);
      asm volatile("s_waitcnt vmcnt(4)" ::: "memory");
    } else {
      asm volatile("s_waitcnt vmcnt(0)" ::: "memory");
    }
    __builtin_amdgcn_s_barrier();
    asm volatile("s_waitcnt lgkmcnt(0)" ::: "memory");
    __builtin_amdgcn_sched_barrier(0);
    __builtin_amdgcn_s_setprio(1);
#pragma unroll
    for (int nf = 2; nf < 4; ++nf)
#pragma unroll
      for (int mf = 0; mf < 8; ++mf)
        acc[mf][nf] = __builtin_amdgcn_mfma_f32_16x16x32_bf16(a[mf], b[nf], acc[mf][nf], 0, 0, 0);
    __builtin_amdgcn_s_setprio(0);
    __builtin_amdgcn_s_barrier();
    // ---------------- ph2 (ks1, nf 0-1) ----------------
#pragma unroll
    for (int mf = 0; mf < 8; ++mf) a[mf] = RD_A(buf, 1, mf);
    b[0] = RD_B(buf, 1, 0); b[1] = RD_B(buf, 1, 1);
    if (pf) QUANT(t + 1, 2);
    __builtin_amdgcn_s_barrier();
    asm volatile("s_waitcnt lgkmcnt(0)" ::: "memory");
    __builtin_amdgcn_sched_barrier(0);
    __builtin_amdgcn_s_setprio(1);
#pragma unroll
    for (int nf = 0; nf < 2; ++nf)
#pragma unroll
      for (int mf = 0; mf < 8; ++mf)
        acc[mf][nf] = __builtin_amdgcn_mfma_f32_16x16x32_bf16(a[mf], b[nf], acc[mf][nf], 0, 0, 0);
    __builtin_amdgcn_s_setprio(0);
    __builtin_amdgcn_s_barrier();
    // ---------------- ph3 (ks1, nf 2-3) ----------------
    b[2] = RD_B(buf, 1, 2); b[3] = RD_B(buf, 1, 3);
    if (pf) {
      QUANT(t + 1, 3);
      asm volatile("s_waitcnt vmcnt(4)" ::: "memory");
    }
    __builtin_amdgcn_s_barrier();
    asm volatile("s_waitcnt lgkmcnt(0)" ::: "memory");
    __builtin_amdgcn_sched_barrier(0);
    __builtin_amdgcn_s_setprio(1);
#pragma unroll
    for (int nf = 2; nf < 4; ++nf)
#pragma unroll
      for (int mf = 0; mf < 8; ++mf)
        acc[mf][nf] = __builtin_amdgcn_mfma_f32_16x16x32_bf16(a[mf], b[nf], acc[mf][nf], 0, 0, 0);
    __builtin_amdgcn_s_setprio(0);
    __builtin_amdgcn_s_barrier();
  }

  // Epilogue: C/D layout col=lane&15, row=(lane>>4)*4+reg (m89-verified)
#pragma unroll
  for (int mf = 0; mf < 8; ++mf) {
#pragma unroll
    for (int nf = 0; nf < 4; ++nf) {
      int mrow = m0 + wr * 128 + mf * 16 + lg * 4;
      int ncol = n0 + wc * 64 + nf * 16 + lr;
#pragma unroll
      for (int r = 0; r < 4; ++r)
        C[(size_t)(mrow + r) * N + ncol] = acc[mf][nf][r];
    }
  }
}

// ---------------- conv(4, causal, depthwise) + silu, x4 vectorized --------
// Writes xc only as bf16 (scan + GEMM2 both read bf16).
__global__ void conv_silu_kernel(const float* __restrict__ xz,
                                 const float* __restrict__ conv_w,
                                 const float* __restrict__ conv_b,
                                 unsigned short* __restrict__ xc_bf) {
  int i4 = blockIdx.x * 256 + threadIdx.x;   // over 2048*1024 float4 groups
  int e4 = i4 & 1023;
  int m = i4 >> 10;
  int l = m & 1023;
  float4 cw0 = reinterpret_cast<const float4*>(conv_w)[e4 * 4 + 0];
  float4 cw1 = reinterpret_cast<const float4*>(conv_w)[e4 * 4 + 1];
  float4 cw2 = reinterpret_cast<const float4*>(conv_w)[e4 * 4 + 2];
  float4 cw3 = reinterpret_cast<const float4*>(conv_w)[e4 * 4 + 3];
  float4 acc = reinterpret_cast<const float4*>(conv_b)[e4];
#pragma unroll
  for (int k = 0; k < 4; ++k) {
    if (l - 3 + k >= 0) {
      float4 xv = reinterpret_cast<const float4*>(xz)[(size_t)(m - 3 + k) * 2048 + e4];
      acc.x = fmaf(xv.x, ((const float*)&cw0)[k], acc.x);
      acc.y = fmaf(xv.y, ((const float*)&cw1)[k], acc.y);
      acc.z = fmaf(xv.z, ((const float*)&cw2)[k], acc.z);
      acc.w = fmaf(xv.w, ((const float*)&cw3)[k], acc.w);
    }
  }
  ushort4 o;
  o.x = f2bf(silu_f(acc.x)); o.y = f2bf(silu_f(acc.y));
  o.z = f2bf(silu_f(acc.z)); o.w = f2bf(silu_f(acc.w));
  reinterpret_cast<ushort4*>(xc_bf)[i4] = o;
}

// ---------------- SSM scan: chunked 2-pass ----------------
__global__ __launch_bounds__(256)
void scan_pass1(const float* __restrict__ delta, const float* __restrict__ dbc,
                const unsigned short* __restrict__ xcb, const float* __restrict__ A_log,
                float* __restrict__ hfin, float* __restrict__ Pprod) {
  __shared__ float Bsh[1024];           // [64][16]
  const int tid = threadIdx.x;
  const int bc = blockIdx.x >> 4;       // b*16 + c
  const int eg = blockIdx.x & 15;
  const int b = bc >> 4, c = bc & 15;
  const int e = eg * 256 + tid;
  const int mb = b * 1024 + c * 64;
  for (int i = tid; i < 1024; i += 256)
    Bsh[i] = dbc[(size_t)(mb + (i >> 4)) * 256 + 128 + (i & 15)];
  __syncthreads();

  float A[16];
  const float4* al = reinterpret_cast<const float4*>(A_log + (size_t)e * 16);
#pragma unroll
  for (int q = 0; q < 4; ++q) {
    float4 v = al[q];
    A[q * 4 + 0] = -__expf(v.x); A[q * 4 + 1] = -__expf(v.y);
    A[q * 4 + 2] = -__expf(v.z); A[q * 4 + 3] = -__expf(v.w);
  }
  float h[16], P[16];
#pragma unroll
  for (int s = 0; s < 16; ++s) { h[s] = 0.f; P[s] = 1.f; }

  for (int ll = 0; ll < 64; ++ll) {
    const size_t m = (size_t)(mb + ll);
    float dl = delta[m * 4096 + e];
    float dxc = dl * bf2f(xcb[m * 4096 + e]);
#pragma unroll
    for (int s = 0; s < 16; ++s) {
      float dA = __expf(dl * A[s]);
      P[s] *= dA;
      h[s] = fmaf(dA, h[s], Bsh[ll * 16 + s] * dxc);
    }
  }
  float* hp = hfin + ((size_t)bc * 4096 + e) * 16;
  float* pp = Pprod + ((size_t)bc * 4096 + e) * 16;
#pragma unroll
  for (int s = 0; s < 16; ++s) { hp[s] = h[s]; pp[s] = P[s]; }
}

__global__ void scan_pass2(float* __restrict__ hfin, const float* __restrict__ Pprod) {
  int idx = blockIdx.x * 256 + threadIdx.x;   // 2*4096*16 = 131072
  int b = idx >> 16;
  int es = idx & 65535;                       // e*16 + s
  float H = 0.f;
  for (int c = 0; c < 16; ++c) {
    size_t o = ((size_t)(b * 16 + c) << 16) + es;
    float hf = hfin[o];
    float Pp = Pprod[o];
    hfin[o] = H;                              // carry-in for chunk c
    H = fmaf(Pp, H, hf);
  }
}

__global__ __launch_bounds__(256)
void scan_pass3(const float* __restrict__ delta, const float* __restrict__ dbc,
                const unsigned short* __restrict__ xcb, const float* __restrict__ xz,
                const float* __restrict__ A_log, const float* __restrict__ Dp,
                const float* __restrict__ hcarry, unsigned short* __restrict__ y_bf) {
  __shared__ float Bsh[1024];           // [64][16]
  __shared__ float Csh[1024];
  const int tid = threadIdx.x;
  const int bc = blockIdx.x >> 4;
  const int eg = blockIdx.x & 15;
  const int b = bc >> 4, c = bc & 15;
  const int e = eg * 256 + tid;
  const int mb = b * 1024 + c * 64;
  for (int i = tid; i < 1024; i += 256) {
    size_t base = (size_t)(mb + (i >> 4)) * 256 + (i & 15);
    Bsh[i] = dbc[base + 128];
    Csh[i] = dbc[base + 144];
  }
  __syncthreads();

  float A[16];
  const float4* al = reinterpret_cast<const float4*>(A_log + (size_t)e * 16);
#pragma unroll
  for (int q = 0; q < 4; ++q) {
    float4 v = al[q];
    A[q * 4 + 0] = -__expf(v.x); A[q * 4 + 1] = -__expf(v.y);
    A[q * 4 + 2] = -__expf(v.z); A[q * 4 + 3] = -__expf(v.w);
  }
  float h[16];
  const float* hp = hcarry + ((size_t)bc * 4096 + e) * 16;
#pragma unroll
  for (int s = 0; s < 16; ++s) h[s] = hp[s];
  const float Dv = Dp[e];

  for (int ll = 0; ll < 64; ++ll) {
    const size_t m = (size_t)(mb + ll);
    float dl = delta[m * 4096 + e];
    float xcv = bf2f(xcb[m * 4096 + e]);
    float dxc = dl * xcv;
    float y = 0.f;
#pragma unroll
    for (int s = 0; s < 16; ++s) {
      float dA = __expf(dl * A[s]);
      h[s] = fmaf(dA, h[s], Bsh[ll * 16 + s] * dxc);
      y = fmaf(h[s], Csh[ll * 16 + s], y);
    }
    float z = xz[m * 8192 + 4096 + e];
    y = (y + xcv * Dv) * silu_f(z);
    y_bf[m * 4096 + e] = f2bf(y);
  }
}

// ---------------------------------------------------------------------------
extern "C" void kernel_launch(void* const* d_in, const int* in_sizes, int n_in,
                              void* d_out, int out_size, void* d_ws, size_t ws_size,
                              hipStream_t stream) {
  const float* x      = (const float*)d_in[0];
  const float* W_in   = (const float*)d_in[1];
  const float* conv_w = (const float*)d_in[2];
  const float* conv_b = (const float*)d_in[3];
  const float* W_x    = (const float*)d_in[4];
  const float* W_dt   = (const float*)d_in[5];
  const float* b_dt   = (const float*)d_in[6];
  const float* A_log  = (const float*)d_in[7];
  const float* Dp     = (const float*)d_in[8];
  const float* W_out  = (const float*)d_in[9];
  float* out = (float*)d_out;
  char* ws = (char*)d_ws;

  // workspace (190,316,544 bytes; time-disjoint aliases):
  // slot0 (ws+0, 33.55 MB): Win_bf -> GEMM2 partials -> delta
  // xz slot (+70254592, 67.11 MB): xz -> GEMM4 partials (xz dead after pass3)
  unsigned short* Win_bf    = (unsigned short*)(ws + 0);
  float*          gpart2    = (float*)(ws + 0);                   // GEMM2 partials
  float*          delta     = (float*)(ws + 0);
  unsigned short* x_bf      = (unsigned short*)(ws + 33554432);
  unsigned short* y_bf      = (unsigned short*)(ws + 33554432);   // alias (after GEMM1)
  unsigned short* Wout_bf   = (unsigned short*)(ws + 50331648);
  unsigned short* Wx_bf     = (unsigned short*)(ws + 67108864);
  unsigned short* Wdt_bf    = (unsigned short*)(ws + 69206016);
  float*          xz        = (float*)(ws + 70254592);
  float*          gpart4    = (float*)(ws + 70254592);            // alias (after pass3)
  unsigned short* xc_bf     = (unsigned short*)(ws + 170917888);
  float*          hfin      = (float*)(ws + 137363456);           // old xc slot (unused now)
  float*          Pprod     = (float*)(ws + 145752064);
  float*          dbc       = (float*)(ws + 187695104);
  unsigned short* dt_bf     = (unsigned short*)(ws + 189792256);

  // fused casts (x, W_in, W_out, W_dt, Wx-pad)
  cast_all<<<30208, 256, 0, stream>>>(x, W_in, W_out, W_dt, W_x,
                                      x_bf, Win_bf, Wout_bf, Wdt_bf, Wx_bf);

  // GEMM1: xz[2048][8192] = x[2048][2048] @ W_in[8192][2048]^T
  gemm_bt_8ph<<<256, 512, 0, stream>>>(x_bf, Win_bf, xz, 2048, 8192, 2048, 8, 2048);

  // conv + silu -> xc_bf
  conv_silu_kernel<<<8192, 256, 0, stream>>>(xz, conv_w, conv_b, xc_bf);

  // GEMM2 (split-K=8): partials[8][2048][256] = xc @ Wx_pad^T
  gemm_bt<<<dim3(2, 16, 8), 256, 0, stream>>>(xc_bf, Wx_bf, gpart2, 2048, 256, 4096, 512, nullptr);
  reduce8_dbc<<<2048, 256, 0, stream>>>(gpart2, dbc, dt_bf);

  // GEMM3 (+fused bias+softplus): delta[2048][4096] = sp(dt @ W_dt^T + b_dt)
  gemm_bt<<<dim3(32, 16, 1), 256, 0, stream>>>(dt_bf, Wdt_bf, delta, 2048, 4096, 128, 128, b_dt);

  // SSM scan: chunked two-pass
  scan_pass1<<<512, 256, 0, stream>>>(delta, dbc, xc_bf, A_log, hfin, Pprod);
  scan_pass2<<<512, 256, 0, stream>>>(hfin, Pprod);
  scan_pass3<<<512, 256, 0, stream>>>(delta, dbc, xc_bf, xz, A_log, Dp, hfin, y_bf);

  // GEMM4 (8ph, split-K=4): partials[4][2048][2048] = y @ W_out^T
  gemm_bt_8ph<<<dim3(64, 1, 4), 512, 0, stream>>>(y_bf, Wout_bf, gpart4, 2048, 2048, 4096, 8, 1024);
  reduce4_out<<<4096, 256, 0, stream>>>(gpart4, out);
}

// Round 9
// 330.101 us; speedup vs baseline: 4.1778x; 1.0606x over previous
//
#include <hip/hip_runtime.h>
#include <cstdint>

// ---------------------------------------------------------------------------
// Mamba block. GEMM1/GEMM4: 256^2 tile 8-wave m201-style pipelined kernel
// (T2+T3+T4+T5); GEMM1 writes bf16 xz, GEMM4 split-K=4 (+reduce4).
// GEMM2: m97 split-K=8 (+fused reduce->dbc,dt_bf). GEMM3: m97 +bias/softplus.
// Scan: chunked 2-pass, bf16 xc/z, fast dA path (r-powers) with generic
// fallback when A[s] != -(s+1).
// ---------------------------------------------------------------------------

typedef __bf16 bf16x8 __attribute__((ext_vector_type(8)));
typedef float f32x4 __attribute__((ext_vector_type(4)));

__device__ __forceinline__ unsigned short f2bf(float f) {
  uint32_t u = __float_as_uint(f);
  u += 0x7FFFu + ((u >> 16) & 1u);   // round-to-nearest-even
  return (unsigned short)(u >> 16);
}

__device__ __forceinline__ float bf2f(unsigned short v) {
  return __uint_as_float(((uint32_t)v) << 16);
}

__device__ __forceinline__ float silu_f(float v) {
  return v / (1.f + __expf(-v));
}

__device__ __forceinline__ float softplus_f(float v) {
  return (v > 20.f) ? v : log1pf(__expf(v));
}

// ---------------- fused cast kernel (all bf16 operand prep) ----------------
__global__ void cast_all(const float* __restrict__ x, const float* __restrict__ W_in,
                         const float* __restrict__ W_out, const float* __restrict__ W_dt,
                         const float* __restrict__ W_x,
                         unsigned short* __restrict__ x_bf, unsigned short* __restrict__ Win_bf,
                         unsigned short* __restrict__ Wout_bf, unsigned short* __restrict__ Wdt_bf,
                         unsigned short* __restrict__ Wx_bf) {
  int i = blockIdx.x * 256 + threadIdx.x;   // over 7,733,248 float4 groups
  const float4* s4; ushort4* d4; int j;
  if (i < 1048576)      { s4 = (const float4*)x;     d4 = (ushort4*)x_bf;    j = i; }
  else if (i < 5242880) { s4 = (const float4*)W_in;  d4 = (ushort4*)Win_bf;  j = i - 1048576; }
  else if (i < 7340032) { s4 = (const float4*)W_out; d4 = (ushort4*)Wout_bf; j = i - 5242880; }
  else if (i < 7471104) { s4 = (const float4*)W_dt;  d4 = (ushort4*)Wdt_bf;  j = i - 7340032; }
  else {
    j = i - 7471104;
    ushort4 o = {0, 0, 0, 0};
    if (j < 163840) {   // 160*4096/4
      float4 v = ((const float4*)W_x)[j];
      o.x = f2bf(v.x); o.y = f2bf(v.y); o.z = f2bf(v.z); o.w = f2bf(v.w);
    }
    ((ushort4*)Wx_bf)[j] = o;
    return;
  }
  float4 v = s4[j];
  ushort4 o; o.x = f2bf(v.x); o.y = f2bf(v.y); o.z = f2bf(v.z); o.w = f2bf(v.w);
  d4[j] = o;
}

// ---------------- m97-style bf16 MFMA GEMM (128^2, BK=32, split-K) --------
#define BM 128
#define BN 128
#define BKK 32

__device__ __forceinline__ void stage_tile(const unsigned short* __restrict__ G,
                                           int ldK, int g0, int k0,
                                           unsigned short* lds, int wave, int lane) {
#pragma unroll
  for (int c = 0; c < 2; ++c) {
    int row = c * 64 + wave * 16 + (lane >> 2);
    int col = (lane & 3) * 8;
    const unsigned short* src = G + (size_t)(g0 + row) * ldK + (k0 + col);
    unsigned short* dst = lds + c * 2048 + wave * 512;  // ushort units
    __builtin_amdgcn_global_load_lds((__attribute__((address_space(1))) void*)(src),
                                     (__attribute__((address_space(3))) void*)(dst),
                                     16, 0, 0);
  }
}

__global__ __launch_bounds__(256)
void gemm_bt(const unsigned short* __restrict__ A, const unsigned short* __restrict__ B,
             float* __restrict__ C, int M, int N, int ldK, int kchunk,
             const float* __restrict__ bias_sp) {
  __shared__ unsigned short As[BM * BKK];
  __shared__ unsigned short Bs[BN * BKK];
  const int tid = threadIdx.x;
  const int wave = tid >> 6, lane = tid & 63;
  const int wr = wave >> 1, wc = wave & 1;
  const int m0 = blockIdx.y * BM, n0 = blockIdx.x * BN;
  const int lr = lane & 15, lg = lane >> 4;
  const int kb = blockIdx.z * kchunk, ke = kb + kchunk;
  C += (size_t)blockIdx.z * M * N;

  f32x4 zero = {0.f, 0.f, 0.f, 0.f};
  f32x4 acc[4][4];
#pragma unroll
  for (int i = 0; i < 4; ++i)
#pragma unroll
    for (int j = 0; j < 4; ++j) acc[i][j] = zero;

  for (int k0 = kb; k0 < ke; k0 += BKK) {
    stage_tile(A, ldK, m0, k0, As, wave, lane);
    stage_tile(B, ldK, n0, k0, Bs, wave, lane);
    __syncthreads();
    bf16x8 af[4], bfr[4];
#pragma unroll
    for (int i = 0; i < 4; ++i)
      af[i] = *reinterpret_cast<const bf16x8*>(&As[(wr * 64 + i * 16 + lr) * BKK + lg * 8]);
#pragma unroll
    for (int j = 0; j < 4; ++j)
      bfr[j] = *reinterpret_cast<const bf16x8*>(&Bs[(wc * 64 + j * 16 + lr) * BKK + lg * 8]);
#pragma unroll
    for (int i = 0; i < 4; ++i)
#pragma unroll
      for (int j = 0; j < 4; ++j)
        acc[i][j] = __builtin_amdgcn_mfma_f32_16x16x32_bf16(af[i], bfr[j], acc[i][j], 0, 0, 0);
    __syncthreads();
  }

#pragma unroll
  for (int i = 0; i < 4; ++i) {
#pragma unroll
    for (int j = 0; j < 4; ++j) {
      int mrow = m0 + wr * 64 + i * 16 + lg * 4;
      int ncol = n0 + wc * 64 + j * 16 + lr;
      if (bias_sp) {
        float bv = bias_sp[ncol];
#pragma unroll
        for (int r = 0; r < 4; ++r)
          C[(size_t)(mrow + r) * N + ncol] = softplus_f(acc[i][j][r] + bv);
      } else {
#pragma unroll
        for (int r = 0; r < 4; ++r)
          C[(size_t)(mrow + r) * N + ncol] = acc[i][j][r];
      }
    }
  }
}

// split-K reducers --------------------------------------------------------
__global__ void reduce8_dbc(const float* __restrict__ p, float* __restrict__ dbc,
                            unsigned short* __restrict__ dt_bf) {
  int i = blockIdx.x * 256 + threadIdx.x;   // over 524288
  float s = 0.f;
#pragma unroll
  for (int c = 0; c < 8; ++c) s += p[(size_t)c * 524288 + i];
  dbc[i] = s;
  int col = i & 255;
  if (col < 128) dt_bf[(size_t)(i >> 8) * 128 + col] = f2bf(s);
}

__global__ void reduce4_out(const float* __restrict__ p, float* __restrict__ out) {
  int i = blockIdx.x * 256 + threadIdx.x;   // over 1048576 float4s
  const float4* p4 = reinterpret_cast<const float4*>(p);
  float4 a = p4[i], b = p4[i + 1048576], c = p4[i + 2097152], d = p4[i + 3145728];
  float4 r;
  r.x = (a.x + b.x) + (c.x + d.x); r.y = (a.y + b.y) + (c.y + d.y);
  r.z = (a.z + b.z) + (c.z + d.z); r.w = (a.w + b.w) + (c.w + d.w);
  reinterpret_cast<float4*>(out)[i] = r;
}

// ---------------- 256^2-tile m201-faithful pipelined GEMM (+split-K) -------
// OT = float (plain) or unsigned short (bf16 output). Schedule/comments: R7.
template <typename OT>
__global__ __launch_bounds__(512, 2)
void gemm_bt_8ph(const unsigned short* __restrict__ A,
                 const unsigned short* __restrict__ B,
                 OT* __restrict__ C, int M, int N, int K, int nbm, int kchunk) {
  __shared__ unsigned short As[2][16384];   // [buf][ks*8192 + row*32 + col]
  __shared__ unsigned short Bs[2][16384];
  const int tid = threadIdx.x;
  const int wid = tid >> 6, lane = tid & 63;
  const int wr = wid >> 2, wc = wid & 3;     // 2 x 4 waves
  const int lr = lane & 15, lg = lane >> 4;

  const int cpx = gridDim.x >> 3;
  const int x = blockIdx.x;
  const int wg = (x & 7) * cpx + (x >> 3);
  const int bm = wg % nbm, bn = wg / nbm;
  const int m0 = bm * 256, n0 = bn * 256;
  const int kb = blockIdx.z * kchunk;
  C += (size_t)blockIdx.z * M * N;

  f32x4 acc[8][4];
  f32x4 zero = {0.f, 0.f, 0.f, 0.f};
#pragma unroll
  for (int i = 0; i < 8; ++i)
#pragma unroll
    for (int j = 0; j < 4; ++j) acc[i][j] = zero;

  const int nt = kchunk / 64;

  auto QUANT = [&](int t, int q) {
    const int buf = t & 1;
    const int ks = q >> 1;
    const unsigned short* G = (q & 1) ? B : A;
    const int g0 = (q & 1) ? n0 : m0;
    unsigned short* lds = ((q & 1) ? &Bs[buf][0] : &As[buf][0]) + ks * 8192;
    const int k0 = kb + t * 64 + ks * 32;
#pragma unroll
    for (int r = 0; r < 2; ++r) {
      int row = r * 128 + (tid >> 2);
      int scol = ((tid & 3) * 8) ^ (((row >> 1) & 3) << 3);
      const unsigned short* src = G + (size_t)(g0 + row) * K + (k0 + scol);
      __builtin_amdgcn_global_load_lds(
          (__attribute__((address_space(1))) const void*)(src),
          (__attribute__((address_space(3))) void*)(lds + r * 4096 + tid * 8),
          16, 0, 0);
    }
  };

  auto RD_A = [&](int buf, int ks, int mf) -> bf16x8 {
    int row = wr * 128 + mf * 16 + lr;
    int col = (lg * 8) ^ (((row >> 1) & 3) << 3);
    return *reinterpret_cast<const bf16x8*>(&As[buf][ks * 8192 + row * 32 + col]);
  };
  auto RD_B = [&](int buf, int ks, int nf) -> bf16x8 {
    int row = wc * 64 + nf * 16 + lr;
    int col = (lg * 8) ^ (((row >> 1) & 3) << 3);
    return *reinterpret_cast<const bf16x8*>(&Bs[buf][ks * 8192 + row * 32 + col]);
  };

  QUANT(0, 0); QUANT(0, 1); QUANT(0, 2); QUANT(0, 3);
  asm volatile("s_waitcnt vmcnt(4)" ::: "memory");
  __builtin_amdgcn_s_barrier();

  bf16x8 a[8], b[4];
  for (int t = 0; t < nt; ++t) {
    const int buf = t & 1;
    const bool pf = (t + 1 < nt);
    // ---------------- ph0 (ks0, nf 0-1) ----------------
#pragma unroll
    for (int mf = 0; mf < 8; ++mf) a[mf] = RD_A(buf, 0, mf);
    b[0] = RD_B(buf, 0, 0); b[1] = RD_B(buf, 0, 1);
    if (pf) {
      QUANT(t + 1, 0);
      asm volatile("s_waitcnt vmcnt(6)" ::: "memory");
    } else {
      asm volatile("s_waitcnt vmcnt(4)" ::: "memory");
    }
    __builtin_amdgcn_s_barrier();
    asm volatile("s_waitcnt lgkmcnt(0)" ::: "memory");
    __builtin_amdgcn_sched_barrier(0);
    __builtin_amdgcn_s_setprio(1);
#pragma unroll
    for (int nf = 0; nf < 2; ++nf)
#pragma unroll
      for (int mf = 0; mf < 8; ++mf)
        acc[mf][nf] = __builtin_amdgcn_mfma_f32_16x16x32_bf16(a[mf], b[nf], acc[mf][nf], 0, 0, 0);
    __builtin_amdgcn_s_setprio(0);
    __builtin_amdgcn_s_barrier();
    // ---------------- ph1 (ks0, nf 2-3) ----------------
    b[2] = RD_B(buf, 0, 2); b[3] = RD_B(buf, 0, 3);
    if (pf) {
      QUANT(t + 1, 1);
      asm volatile("s_waitcnt vmcnt(4)" ::: "memory");
    } else {
      asm volatile("s_waitcnt vmcnt(0)" ::: "memory");
    }
    __builtin_amdgcn_s_barrier();
    asm volatile("s_waitcnt lgkmcnt(0)" ::: "memory");
    __builtin_amdgcn_sched_barrier(0);
    __builtin_amdgcn_s_setprio(1);
#pragma unroll
    for (int nf = 2; nf < 4; ++nf)
#pragma unroll
      for (int mf = 0; mf < 8; ++mf)
        acc[mf][nf] = __builtin_amdgcn_mfma_f32_16x16x32_bf16(a[mf], b[nf], acc[mf][nf], 0, 0, 0);
    __builtin_amdgcn_s_setprio(0);
    __builtin_amdgcn_s_barrier();
    // ---------------- ph2 (ks1, nf 0-1) ----------------
#pragma unroll
    for (int mf = 0; mf < 8; ++mf) a[mf] = RD_A(buf, 1, mf);
    b[0] = RD_B(buf, 1, 0); b[1] = RD_B(buf, 1, 1);
    if (pf) QUANT(t + 1, 2);
    __builtin_amdgcn_s_barrier();
    asm volatile("s_waitcnt lgkmcnt(0)" ::: "memory");
    __builtin_amdgcn_sched_barrier(0);
    __builtin_amdgcn_s_setprio(1);
#pragma unroll
    for (int nf = 0; nf < 2; ++nf)
#pragma unroll
      for (int mf = 0; mf < 8; ++mf)
        acc[mf][nf] = __builtin_amdgcn_mfma_f32_16x16x32_bf16(a[mf], b[nf], acc[mf][nf], 0, 0, 0);
    __builtin_amdgcn_s_setprio(0);
    __builtin_amdgcn_s_barrier();
    // ---------------- ph3 (ks1, nf 2-3) ----------------
    b[2] = RD_B(buf, 1, 2); b[3] = RD_B(buf, 1, 3);
    if (pf) {
      QUANT(t + 1, 3);
      asm volatile("s_waitcnt vmcnt(4)" ::: "memory");
    }
    __builtin_amdgcn_s_barrier();
    asm volatile("s_waitcnt lgkmcnt(0)" ::: "memory");
    __builtin_amdgcn_sched_barrier(0);
    __builtin_amdgcn_s_setprio(1);
#pragma unroll
    for (int nf = 2; nf < 4; ++nf)
#pragma unroll
      for (int mf = 0; mf < 8; ++mf)
        acc[mf][nf] = __builtin_amdgcn_mfma_f32_16x16x32_bf16(a[mf], b[nf], acc[mf][nf], 0, 0, 0);
    __builtin_amdgcn_s_setprio(0);
    __builtin_amdgcn_s_barrier();
  }

  // Epilogue: C/D layout col=lane&15, row=(lane>>4)*4+reg (m89-verified)
#pragma unroll
  for (int mf = 0; mf < 8; ++mf) {
#pragma unroll
    for (int nf = 0; nf < 4; ++nf) {
      int mrow = m0 + wr * 128 + mf * 16 + lg * 4;
      int ncol = n0 + wc * 64 + nf * 16 + lr;
#pragma unroll
      for (int r = 0; r < 4; ++r) {
        if constexpr (sizeof(OT) == 2)
          C[(size_t)(mrow + r) * N + ncol] = (OT)f2bf(acc[mf][nf][r]);
        else
          C[(size_t)(mrow + r) * N + ncol] = (OT)acc[mf][nf][r];
      }
    }
  }
}

// ---------------- conv(4, causal, depthwise) + silu (bf16 in/out) ---------
__global__ void conv_silu_kernel(const unsigned short* __restrict__ xzb,
                                 const float* __restrict__ conv_w,
                                 const float* __restrict__ conv_b,
                                 unsigned short* __restrict__ xc_bf) {
  int i4 = blockIdx.x * 256 + threadIdx.x;   // over 2048*1024 groups of 4
  int e4 = i4 & 1023;
  int m = i4 >> 10;
  int l = m & 1023;
  float4 cw0 = reinterpret_cast<const float4*>(conv_w)[e4 * 4 + 0];
  float4 cw1 = reinterpret_cast<const float4*>(conv_w)[e4 * 4 + 1];
  float4 cw2 = reinterpret_cast<const float4*>(conv_w)[e4 * 4 + 2];
  float4 cw3 = reinterpret_cast<const float4*>(conv_w)[e4 * 4 + 3];
  float4 acc = reinterpret_cast<const float4*>(conv_b)[e4];
#pragma unroll
  for (int k = 0; k < 4; ++k) {
    if (l - 3 + k >= 0) {
      ushort4 xv = reinterpret_cast<const ushort4*>(xzb)[(size_t)(m - 3 + k) * 2048 + e4];
      acc.x = fmaf(bf2f(xv.x), ((const float*)&cw0)[k], acc.x);
      acc.y = fmaf(bf2f(xv.y), ((const float*)&cw1)[k], acc.y);
      acc.z = fmaf(bf2f(xv.z), ((const float*)&cw2)[k], acc.z);
      acc.w = fmaf(bf2f(xv.w), ((const float*)&cw3)[k], acc.w);
    }
  }
  ushort4 o;
  o.x = f2bf(silu_f(acc.x)); o.y = f2bf(silu_f(acc.y));
  o.z = f2bf(silu_f(acc.z)); o.w = f2bf(silu_f(acc.w));
  reinterpret_cast<ushort4*>(xc_bf)[i4] = o;
}

// ---------------- SSM scan: chunked 2-pass ----------------
// dA fast path: if A[s] == -(s+1) (true for this model: A_log=log(1..16)),
// dA[s] = r^(s+1), r = exp(-delta) -- 1 exp + depth-4 multiply tree instead
// of 16 exps. Generic fallback otherwise (uniform branch).
__device__ __forceinline__ void dA_powers(float r, float* dA) {
  float r2 = r * r, r4 = r2 * r2, r8 = r4 * r4;
  dA[0] = r;        dA[1] = r2;       dA[2] = r2 * r;   dA[3] = r4;
  dA[4] = r4 * r;   dA[5] = r4 * r2;  dA[6] = dA[5] * r; dA[7] = r8;
  dA[8] = r8 * r;   dA[9] = r8 * r2;  dA[10] = dA[9] * r; dA[11] = r8 * r4;
  dA[12] = dA[11] * r; dA[13] = dA[11] * r2; dA[14] = dA[13] * r; dA[15] = r8 * r8;
}

__global__ __launch_bounds__(256)
void scan_pass1(const float* __restrict__ delta, const float* __restrict__ dbc,
                const unsigned short* __restrict__ xcb, const float* __restrict__ A_log,
                float* __restrict__ hfin, float* __restrict__ Pprod) {
  __shared__ float Bsh[1024];           // [64][16]
  const int tid = threadIdx.x;
  const int bc = blockIdx.x >> 4;       // b*16 + c
  const int eg = blockIdx.x & 15;
  const int b = bc >> 4, c = bc & 15;
  const int e = eg * 256 + tid;
  const int mb = b * 1024 + c * 64;
  for (int i = tid; i < 1024; i += 256)
    Bsh[i] = dbc[(size_t)(mb + (i >> 4)) * 256 + 128 + (i & 15)];
  __syncthreads();

  float A[16];
  const float4* al = reinterpret_cast<const float4*>(A_log + (size_t)e * 16);
#pragma unroll
  for (int q = 0; q < 4; ++q) {
    float4 v = al[q];
    A[q * 4 + 0] = -__expf(v.x); A[q * 4 + 1] = -__expf(v.y);
    A[q * 4 + 2] = -__expf(v.z); A[q * 4 + 3] = -__expf(v.w);
  }
  bool fastp = true;
#pragma unroll
  for (int s = 0; s < 16; ++s)
    fastp = fastp && (fabsf(A[s] + (float)(s + 1)) <= 1e-5f * (float)(s + 1));

  float h[16], P[16];
#pragma unroll
  for (int s = 0; s < 16; ++s) { h[s] = 0.f; P[s] = 1.f; }

  if (fastp) {
    for (int ll = 0; ll < 64; ++ll) {
      const size_t m = (size_t)(mb + ll);
      float dl = delta[m * 4096 + e];
      float dxc = dl * bf2f(xcb[m * 4096 + e]);
      float dA[16];
      dA_powers(__expf(-dl), dA);
#pragma unroll
      for (int s = 0; s < 16; ++s) {
        P[s] *= dA[s];
        h[s] = fmaf(dA[s], h[s], Bsh[ll * 16 + s] * dxc);
      }
    }
  } else {
    for (int ll = 0; ll < 64; ++ll) {
      const size_t m = (size_t)(mb + ll);
      float dl = delta[m * 4096 + e];
      float dxc = dl * bf2f(xcb[m * 4096 + e]);
#pragma unroll
      for (int s = 0; s < 16; ++s) {
        float dA = __expf(dl * A[s]);
        P[s] *= dA;
        h[s] = fmaf(dA, h[s], Bsh[ll * 16 + s] * dxc);
      }
    }
  }
  float* hp = hfin + ((size_t)bc * 4096 + e) * 16;
  float* pp = Pprod + ((size_t)bc * 4096 + e) * 16;
#pragma unroll
  for (int s = 0; s < 16; ++s) { hp[s] = h[s]; pp[s] = P[s]; }
}

__global__ void scan_pass2(float* __restrict__ hfin, const float* __restrict__ Pprod) {
  int idx = blockIdx.x * 256 + threadIdx.x;   // 2*4096*16 = 131072
  int b = idx >> 16;
  int es = idx & 65535;                       // e*16 + s
  float H = 0.f;
  for (int c = 0; c < 16; ++c) {
    size_t o = ((size_t)(b * 16 + c) << 16) + es;
    float hf = hfin[o];
    float Pp = Pprod[o];
    hfin[o] = H;                              // carry-in for chunk c
    H = fmaf(Pp, H, hf);
  }
}

__global__ __launch_bounds__(256)
void scan_pass3(const float* __restrict__ delta, const float* __restrict__ dbc,
                const unsigned short* __restrict__ xcb, const unsigned short* __restrict__ xzb,
                const float* __restrict__ A_log, const float* __restrict__ Dp,
                const float* __restrict__ hcarry, unsigned short* __restrict__ y_bf) {
  __shared__ float Bsh[1024];           // [64][16]
  __shared__ float Csh[1024];
  const int tid = threadIdx.x;
  const int bc = blockIdx.x >> 4;
  const int eg = blockIdx.x & 15;
  const int b = bc >> 4, c = bc & 15;
  const int e = eg * 256 + tid;
  const int mb = b * 1024 + c * 64;
  for (int i = tid; i < 1024; i += 256) {
    size_t base = (size_t)(mb + (i >> 4)) * 256 + (i & 15);
    Bsh[i] = dbc[base + 128];
    Csh[i] = dbc[base + 144];
  }
  __syncthreads();

  float A[16];
  const float4* al = reinterpret_cast<const float4*>(A_log + (size_t)e * 16);
#pragma unroll
  for (int q = 0; q < 4; ++q) {
    float4 v = al[q];
    A[q * 4 + 0] = -__expf(v.x); A[q * 4 + 1] = -__expf(v.y);
    A[q * 4 + 2] = -__expf(v.z); A[q * 4 + 3] = -__expf(v.w);
  }
  bool fastp = true;
#pragma unroll
  for (int s = 0; s < 16; ++s)
    fastp = fastp && (fabsf(A[s] + (float)(s + 1)) <= 1e-5f * (float)(s + 1));

  float h[16];
  const float* hp = hcarry + ((size_t)bc * 4096 + e) * 16;
#pragma unroll
  for (int s = 0; s < 16; ++s) h[s] = hp[s];
  const float Dv = Dp[e];

  if (fastp) {
    for (int ll = 0; ll < 64; ++ll) {
      const size_t m = (size_t)(mb + ll);
      float dl = delta[m * 4096 + e];
      float xcv = bf2f(xcb[m * 4096 + e]);
      float dxc = dl * xcv;
      float dA[16];
      dA_powers(__expf(-dl), dA);
      float y = 0.f;
#pragma unroll
      for (int s = 0; s < 16; ++s) {
        h[s] = fmaf(dA[s], h[s], Bsh[ll * 16 + s] * dxc);
        y = fmaf(h[s], Csh[ll * 16 + s], y);
      }
      float z = bf2f(xzb[m * 8192 + 4096 + e]);
      y = (y + xcv * Dv) * silu_f(z);
      y_bf[m * 4096 + e] = f2bf(y);
    }
  } else {
    for (int ll = 0; ll < 64; ++ll) {
      const size_t m = (size_t)(mb + ll);
      float dl = delta[m * 4096 + e];
      float xcv = bf2f(xcb[m * 4096 + e]);
      float dxc = dl * xcv;
      float y = 0.f;
#pragma unroll
      for (int s = 0; s < 16; ++s) {
        float dA = __expf(dl * A[s]);
        h[s] = fmaf(dA, h[s], Bsh[ll * 16 + s] * dxc);
        y = fmaf(h[s], Csh[ll * 16 + s], y);
      }
      float z = bf2f(xzb[m * 8192 + 4096 + e]);
      y = (y + xcv * Dv) * silu_f(z);
      y_bf[m * 4096 + e] = f2bf(y);
    }
  }
}

// ---------------------------------------------------------------------------
extern "C" void kernel_launch(void* const* d_in, const int* in_sizes, int n_in,
                              void* d_out, int out_size, void* d_ws, size_t ws_size,
                              hipStream_t stream) {
  const float* x      = (const float*)d_in[0];
  const float* W_in   = (const float*)d_in[1];
  const float* conv_w = (const float*)d_in[2];
  const float* conv_b = (const float*)d_in[3];
  const float* W_x    = (const float*)d_in[4];
  const float* W_dt   = (const float*)d_in[5];
  const float* b_dt   = (const float*)d_in[6];
  const float* A_log  = (const float*)d_in[7];
  const float* Dp     = (const float*)d_in[8];
  const float* W_out  = (const float*)d_in[9];
  float* out = (float*)d_out;
  char* ws = (char*)d_ws;

  // workspace (190,316,544 B; time-disjoint aliases):
  // slot0 (+0, 33.5 MB): Win_bf -> gpart2 -> delta
  // +33554432 (16.8 MB): x_bf -> y_bf
  // +50331648 (16.8 MB): Wout_bf | +67108864 Wx_bf | +69206016 Wdt_bf
  // +70254592 (33.5 MB): xz_bf (bf16 [2048][8192])
  // +103809024 (67.1 MB): gpart4 (after pass3) ; hfin/Pprod (during scan)
  // +170917888 (16.8 MB): xc_bf | +187695104 dbc | +189792256 dt_bf
  unsigned short* Win_bf    = (unsigned short*)(ws + 0);
  float*          gpart2    = (float*)(ws + 0);
  float*          delta     = (float*)(ws + 0);
  unsigned short* x_bf      = (unsigned short*)(ws + 33554432);
  unsigned short* y_bf      = (unsigned short*)(ws + 33554432);   // alias (after GEMM1)
  unsigned short* Wout_bf   = (unsigned short*)(ws + 50331648);
  unsigned short* Wx_bf     = (unsigned short*)(ws + 67108864);
  unsigned short* Wdt_bf    = (unsigned short*)(ws + 69206016);
  unsigned short* xz_bf     = (unsigned short*)(ws + 70254592);
  float*          gpart4    = (float*)(ws + 103809024);           // alias (after pass3)
  float*          hfin      = (float*)(ws + 103809024);           // scan-time
  float*          Pprod     = (float*)(ws + 112197632);
  unsigned short* xc_bf     = (unsigned short*)(ws + 170917888);
  float*          dbc       = (float*)(ws + 187695104);
  unsigned short* dt_bf     = (unsigned short*)(ws + 189792256);

  // fused casts (x, W_in, W_out, W_dt, Wx-pad)
  cast_all<<<30208, 256, 0, stream>>>(x, W_in, W_out, W_dt, W_x,
                                      x_bf, Win_bf, Wout_bf, Wdt_bf, Wx_bf);

  // GEMM1: xz_bf[2048][8192] = x @ W_in^T (bf16 output)
  gemm_bt_8ph<unsigned short><<<256, 512, 0, stream>>>(x_bf, Win_bf, xz_bf, 2048, 8192, 2048, 8, 2048);

  // conv + silu -> xc_bf
  conv_silu_kernel<<<8192, 256, 0, stream>>>(xz_bf, conv_w, conv_b, xc_bf);

  // GEMM2 (split-K=8): partials[8][2048][256] = xc @ Wx_pad^T
  gemm_bt<<<dim3(2, 16, 8), 256, 0, stream>>>(xc_bf, Wx_bf, gpart2, 2048, 256, 4096, 512, nullptr);
  reduce8_dbc<<<2048, 256, 0, stream>>>(gpart2, dbc, dt_bf);

  // GEMM3 (+fused bias+softplus): delta[2048][4096] = sp(dt @ W_dt^T + b_dt)
  gemm_bt<<<dim3(32, 16, 1), 256, 0, stream>>>(dt_bf, Wdt_bf, delta, 2048, 4096, 128, 128, b_dt);

  // SSM scan: chunked two-pass
  scan_pass1<<<512, 256, 0, stream>>>(delta, dbc, xc_bf, A_log, hfin, Pprod);
  scan_pass2<<<512, 256, 0, stream>>>(hfin, Pprod);
  scan_pass3<<<512, 256, 0, stream>>>(delta, dbc, xc_bf, xz_bf, A_log, Dp, hfin, y_bf);

  // GEMM4 (8ph, split-K=4): partials[4][2048][2048] = y @ W_out^T
  gemm_bt_8ph<float><<<dim3(64, 1, 4), 512, 0, stream>>>(y_bf, Wout_bf, gpart4, 2048, 2048, 4096, 8, 1024);
  reduce4_out<<<4096, 256, 0, stream>>>(gpart4, out);
}